// Round 10
// baseline (1148.610 us; speedup 1.0000x reference)
//
#include <hip/hip_runtime.h>

// SSHA block. Round 10: attention-apply via transposed-H MFMA path.
//   H''[nl,t',o][k=vp*8+s] (K=200, bf16) = sum_c x[n,t',vp,c]*W[o,s,c]
//     (k_hgemm: round-7 body + scatter C-write; 4n chunks in qfull region)
//   k_apply (per n,t; NO LDS, NO barriers):
//     O[o,v] = sum_w sum_k H''[t+w-1,o,k] * A''[v, w*200+k]
//     epilogue: y1 = leaky(x + BN(O + b_out))
//   k_scores emits A''=attTb[n][v 32][w*200+vp*8+s] (v>=25 rows zeroed).
// Everything else unchanged from round 9.
// Shapes: N=16, T=288, V=25, C=128, S=8, IC=16, W=3, U=75, TP=290.

#define NN 16
#define TT 288
#define VV 25
#define CC 128
#define SS 8
#define UU 75
#define TP 290
#define EPSF 1e-5f

typedef __attribute__((ext_vector_type(8))) short bf16x8;
typedef __attribute__((ext_vector_type(4))) float f32x4;

static __device__ __forceinline__ ushort f2bf(float f) {
  uint u = __float_as_uint(f);
  u = (u + 0x7FFFu + ((u >> 16) & 1u)) >> 16;
  return (ushort)u;
}

// ---------------- K0: weight converts ----------------
__global__ __launch_bounds__(256) void k_wcvt(
    const float* __restrict__ w_out, const float* __restrict__ w_k,
    const float* __restrict__ w_q, const float* __restrict__ w_ff,
    ushort* __restrict__ wb, ushort* __restrict__ wkqb,
    ushort* __restrict__ wffb) {
  int i = blockIdx.x * 256 + threadIdx.x;  // 180224 total
  if (i < 131072) {
    int j = i >> 7, c = i & 127;
    int s = j >> 7, o = j & 127;
    wb[i] = f2bf(w_out[(o << 10) + (s << 7) + c]);
  } else {
    int j = i - 131072;
    if (j < 16384) wkqb[j] = f2bf(w_k[j]);
    else if (j < 32768) wkqb[j] = f2bf(w_q[j - 16384]);
    else wffb[j - 32768] = f2bf(w_ff[j - 32768]);
  }
}

// ---------------- K1: k/q 1x1 convs as bf16 MFMA GEMM ----------------
__global__ __launch_bounds__(256) void k_qkg(
    const float* __restrict__ x, const ushort* __restrict__ wkqb,
    const float* __restrict__ b_k, const float* __restrict__ b_q,
    ushort* __restrict__ kb, ushort* __restrict__ qb) {
  __shared__ __align__(16) ushort As[8][128][8];
  __shared__ __align__(16) ushort Bs[8][128][8];
  const int bm = blockIdx.x, by = blockIdx.y;
  const int gm0 = bm << 7;
  const int tid = threadIdx.x;
  const int lane = tid & 63, wid = tid >> 6;
  const int wm = wid >> 1, wn = wid & 1;
  const int srow = tid & 127;
  const int skg0 = tid >> 7;
  const ushort* wsrc = wkqb + by * 16384;
  f32x4 acc[4][4] = {};
  for (int kh = 0; kh < 2; ++kh) {
    __syncthreads();
#pragma unroll
    for (int j = 0; j < 4; ++j) {
      int kg = skg0 + 2 * j;
      const float* xp = x + (((size_t)(gm0 + srow)) << 7) + kh * 64 + kg * 8;
      float4 a0 = *(const float4*)xp;
      float4 a1 = *(const float4*)(xp + 4);
      uint4 pk;
      pk.x = (uint)f2bf(a0.x) | ((uint)f2bf(a0.y) << 16);
      pk.y = (uint)f2bf(a0.z) | ((uint)f2bf(a0.w) << 16);
      pk.z = (uint)f2bf(a1.x) | ((uint)f2bf(a1.y) << 16);
      pk.w = (uint)f2bf(a1.z) | ((uint)f2bf(a1.w) << 16);
      *(uint4*)&As[kg][srow][0] = pk;
      *(uint4*)&Bs[kg][srow][0] =
          *(const uint4*)&wsrc[(srow << 7) + kh * 64 + kg * 8];
    }
    __syncthreads();
#pragma unroll
    for (int ks = 0; ks < 2; ++ks) {
      int g = ks * 4 + (lane >> 4);
      bf16x8 af[4], bfr[4];
#pragma unroll
      for (int mi = 0; mi < 4; ++mi)
        af[mi] = *(const bf16x8*)&As[g][wm * 64 + mi * 16 + (lane & 15)][0];
#pragma unroll
      for (int ni = 0; ni < 4; ++ni)
        bfr[ni] = *(const bf16x8*)&Bs[g][wn * 64 + ni * 16 + (lane & 15)][0];
#pragma unroll
      for (int mi = 0; mi < 4; ++mi)
#pragma unroll
        for (int ni = 0; ni < 4; ++ni)
          acc[mi][ni] = __builtin_amdgcn_mfma_f32_16x16x32_bf16(
              af[mi], bfr[ni], acc[mi][ni], 0, 0, 0);
    }
  }
  const int l15 = lane & 15, l4 = lane >> 4;
  const float* bias = by ? b_q : b_k;
#pragma unroll
  for (int ni = 0; ni < 4; ++ni) {
    int col = wn * 64 + ni * 16 + l15;
    float bb = bias[col];
#pragma unroll
    for (int mi = 0; mi < 4; ++mi) {
#pragma unroll
      for (int reg = 0; reg < 4; ++reg) {
        int row = gm0 + wm * 64 + mi * 16 + (l4 << 2) + reg;
        ushort val = f2bf(acc[mi][ni][reg] + bb);
        if (by == 0) {
          kb[((size_t)row << 7) + col] = val;
        } else {
          int n = row / 7200;
          qb[((size_t)(row + n * 50 + 25) << 7) + col] = val;
        }
      }
    }
  }
}

// qb pad rows (tp=0, tp=289): bias-only.
__global__ __launch_bounds__(256) void k_qkpad(const float* __restrict__ b_q,
                                               ushort* __restrict__ qb) {
  int i = blockIdx.x * 256 + threadIdx.x;  // 16*2*25*128
  int o = i & 127;
  int r = i >> 7;
  int v = r % 25;
  int e = (r / 25) & 1;
  int n = r / 50;
  int tp = e ? 289 : 0;
  qb[((size_t)((n * TP + tp) * VV + v) << 7) + o] = f2bf(b_q[o]);
}

// ---------------- K2: scores (bf16 MFMA) + fused softmax -> attTb bf16 ----------------
// attTb[n][v(32)][w*200 + vp*8 + s] (1 n slice = 32*600 sh); v>=25 rows zero.
__global__ __launch_bounds__(512) void k_scores(
    const ushort* __restrict__ kb, const ushort* __restrict__ qb,
    const float* __restrict__ alphas, const float* __restrict__ att0,
    ushort* __restrict__ attTb) {
  __shared__ float red[8][2640];  // [wave][u(80) * 33 + v(32)]
  __shared__ float scl[1875];
  __shared__ float mx[25];
  __shared__ float den[25];
  const int bx = blockIdx.x;
  const int n = bx >> 3, s = bx & 7;
  const int tid = threadIdx.x;
  const int lane = tid & 63, wid = tid >> 6;
  const int l15 = lane & 15, l4 = lane >> 4;
  const int dt = l4 >> 1;
  const int sic = s * 16 + (l4 & 1) * 8;
  int qoff[5];
#pragma unroll
  for (int tu = 0; tu < 5; ++tu) {
    int u = tu * 16 + l15;
    int w = u / 25, vp = u - w * 25;
    qoff[tu] = (w * 25 + vp) * 128 + sic;
  }
  const bool qv4 = (64 + l15) < 75;
  const bool kv1 = (16 + l15) < 25;
  int koff0 = l15 * 128 + sic;
  int koff1 = (16 + l15) * 128 + sic;
  const ushort* qbase = qb + (size_t)n * 928000 + (size_t)dt * 3200;
  const ushort* kbase = kb + (size_t)n * 921600 + (size_t)dt * 3200;
  f32x4 acc[5][2] = {};
  const bf16x8 zf = {};
  for (int kk = wid; kk < 144; kk += 8) {
    const ushort* qp = qbase + kk * 6400;
    const ushort* kp = kbase + kk * 6400;
    bf16x8 a[5], b[2];
#pragma unroll
    for (int tu = 0; tu < 4; ++tu) a[tu] = *(const bf16x8*)(qp + qoff[tu]);
    a[4] = qv4 ? *(const bf16x8*)(qp + qoff[4]) : zf;
    b[0] = *(const bf16x8*)(kp + koff0);
    b[1] = kv1 ? *(const bf16x8*)(kp + koff1) : zf;
#pragma unroll
    for (int tu = 0; tu < 5; ++tu)
#pragma unroll
      for (int tv = 0; tv < 2; ++tv)
        acc[tu][tv] = __builtin_amdgcn_mfma_f32_16x16x32_bf16(
            a[tu], b[tv], acc[tu][tv], 0, 0, 0);
  }
#pragma unroll
  for (int tu = 0; tu < 5; ++tu)
#pragma unroll
    for (int tv = 0; tv < 2; ++tv) {
#pragma unroll
      for (int reg = 0; reg < 4; ++reg)
        red[wid][(tu * 16 + l4 * 4 + reg) * 33 + tv * 16 + l15] =
            acc[tu][tv][reg];
    }
  __syncthreads();
  const float inv = 1.0f / 4608.0f;
  for (int i = tid; i < 1875; i += 512) {
    int u = i / 25, v = i - u * 25;
    float a = 0.f;
#pragma unroll
    for (int w = 0; w < 8; ++w) a += red[w][u * 33 + v];
    scl[i] = a * inv;
  }
  __syncthreads();
  if (tid < 25) {
    float m = -1e30f;
    for (int u = 0; u < 75; ++u) m = fmaxf(m, scl[u * 25 + tid]);
    float d = 0.f;
    for (int u = 0; u < 75; ++u) d += expf(scl[u * 25 + tid] - m);
    mx[tid] = m;
    den[tid] = d;
  }
  __syncthreads();
  const float alpha = alphas[s];
  ushort* op = attTb + (size_t)n * 19200 + s;  // this block fills its s-lane
  for (int i = tid; i < 2400; i += 512) {      // 32 v x 75 u
    int v = i / 75, u = i - v * 75;
    int w = u / 25, vp = u - w * 25;
    float val = 0.f;
    if (v < 25)
      val = expf(scl[u * 25 + v] - mx[v]) / den[v] * alpha +
            att0[(s * 75 + u) * 25 + v];
    op[v * 600 + w * 200 + vp * 8] = f2bf(val);
  }
}

// ---------------- K3a: H-GEMM chunk (bf16 MFMA) -> transposed H'' ----------------
// H''[((nl*288+t')*128 + o)*200 + vp*8 + s]; rows (nl,t',vp), cols j=(s,o).
__global__ __launch_bounds__(256) void k_hgemm(const float* __restrict__ x,
                                               const ushort* __restrict__ wb,
                                               ushort* __restrict__ Hc, int n0) {
  __shared__ __align__(16) ushort As[8][128][8];
  __shared__ __align__(16) ushort Bs[8][128][8];
  const int bx = blockIdx.x;
  const int bm = bx >> 3, bn = bx & 7;
  const int gm0 = bm << 7, gn0 = bn << 7;
  const int tid = threadIdx.x;
  const int lane = tid & 63, wid = tid >> 6;
  const int wm = wid >> 1, wn = wid & 1;
  const int srow = tid & 127;
  const int skg0 = tid >> 7;
  const size_t xbase = ((size_t)n0 * 7200 + gm0) << 7;
  f32x4 acc[4][4] = {};
  for (int kh = 0; kh < 2; ++kh) {
    __syncthreads();
#pragma unroll
    for (int j = 0; j < 4; ++j) {
      int kg = skg0 + 2 * j;
      const float* xp = x + xbase + ((size_t)srow << 7) + kh * 64 + kg * 8;
      float4 a0 = *(const float4*)xp;
      float4 a1 = *(const float4*)(xp + 4);
      uint4 pk;
      pk.x = (uint)f2bf(a0.x) | ((uint)f2bf(a0.y) << 16);
      pk.y = (uint)f2bf(a0.z) | ((uint)f2bf(a0.w) << 16);
      pk.z = (uint)f2bf(a1.x) | ((uint)f2bf(a1.y) << 16);
      pk.w = (uint)f2bf(a1.z) | ((uint)f2bf(a1.w) << 16);
      *(uint4*)&As[kg][srow][0] = pk;
      *(uint4*)&Bs[kg][srow][0] =
          *(const uint4*)&wb[((size_t)(gn0 + srow) << 7) + kh * 64 + kg * 8];
    }
    __syncthreads();
#pragma unroll
    for (int ks = 0; ks < 2; ++ks) {
      int g = ks * 4 + (lane >> 4);
      bf16x8 af[4], bfr[4];
#pragma unroll
      for (int mi = 0; mi < 4; ++mi)
        af[mi] = *(const bf16x8*)&As[g][wm * 64 + mi * 16 + (lane & 15)][0];
#pragma unroll
      for (int ni = 0; ni < 4; ++ni)
        bfr[ni] = *(const bf16x8*)&Bs[g][wn * 64 + ni * 16 + (lane & 15)][0];
#pragma unroll
      for (int mi = 0; mi < 4; ++mi)
#pragma unroll
        for (int ni = 0; ni < 4; ++ni)
          acc[mi][ni] = __builtin_amdgcn_mfma_f32_16x16x32_bf16(
              af[mi], bfr[ni], acc[mi][ni], 0, 0, 0);
    }
  }
  const int l15 = lane & 15, l4 = lane >> 4;
  const int r0 = gm0 + wm * 64;
  const int c0 = gn0 + wn * 64;
#pragma unroll
  for (int mi = 0; mi < 4; ++mi)
#pragma unroll
    for (int ni = 0; ni < 4; ++ni) {
      int col = c0 + ni * 16 + l15;
      int s = col >> 7, o = col & 127;
#pragma unroll
      for (int reg = 0; reg < 4; ++reg) {
        int row = r0 + mi * 16 + (l4 << 2) + reg;
        int nl = row / 7200, rr = row - nl * 7200;
        int tp = rr / 25, vp = rr - tp * 25;
        Hc[((size_t)((nl * TT + tp) * 128) + o) * 200 + vp * 8 + s] =
            f2bf(acc[mi][ni][reg]);
      }
    }
}

// ---------------- K3b: apply = H''.A'' MFMA + b_out + BN + leaky residual ----------------
// Grid (288, 4): x -> t (XCD-swizzled), y = nl. 256 thr = 4 waves; wave owns
// o-range [wid*32, wid*32+32). No LDS, no barriers.
__global__ __launch_bounds__(256) void k_apply(
    const ushort* __restrict__ Hc, const ushort* __restrict__ attTb,
    const float* __restrict__ x, const float* __restrict__ b_out,
    const float* __restrict__ g_out, const float* __restrict__ beta_out,
    const float* __restrict__ m_out, const float* __restrict__ v_out,
    float* __restrict__ y1, int n0) {
  const int xs = blockIdx.x;
  const int t = (xs & 7) * 36 + (xs >> 3);  // 288 = 8 XCD chunks of 36
  const int nl = blockIdx.y;
  const int n = n0 + nl;
  const int tid = threadIdx.x;
  const int lane = tid & 63, wid = tid >> 6;
  const int l15 = lane & 15, l4 = lane >> 4;
  const bf16x8 zf = {};
  f32x4 acc[2][2] = {};  // [mi(o-tile)][nj(v-tile)]
  const ushort* ap = attTb + (size_t)n * 19200;
  for (int w = 0; w < 3; ++w) {
    int tp = t + w - 1;
    if (tp < 0 || tp >= TT) continue;
    const ushort* hp = Hc + (size_t)((nl * TT + tp) * 128) * 200;
#pragma unroll
    for (int ks = 0; ks < 7; ++ks) {
      int k0 = ks * 32 + l4 * 8;
      bool kv = k0 < 200;
      bf16x8 h0 = kv ? *(const bf16x8*)&hp[(wid * 32 + l15) * 200 + k0] : zf;
      bf16x8 h1 =
          kv ? *(const bf16x8*)&hp[(wid * 32 + 16 + l15) * 200 + k0] : zf;
      bf16x8 a0 = kv ? *(const bf16x8*)&ap[l15 * 600 + w * 200 + k0] : zf;
      bf16x8 a1 =
          kv ? *(const bf16x8*)&ap[(16 + l15) * 600 + w * 200 + k0] : zf;
      acc[0][0] = __builtin_amdgcn_mfma_f32_16x16x32_bf16(h0, a0, acc[0][0], 0, 0, 0);
      acc[0][1] = __builtin_amdgcn_mfma_f32_16x16x32_bf16(h0, a1, acc[0][1], 0, 0, 0);
      acc[1][0] = __builtin_amdgcn_mfma_f32_16x16x32_bf16(h1, a0, acc[1][0], 0, 0, 0);
      acc[1][1] = __builtin_amdgcn_mfma_f32_16x16x32_bf16(h1, a1, acc[1][1], 0, 0, 0);
    }
  }
  // epilogue: BN + leaky(x + .). col=l15 -> v, row=l4*4+reg -> o (consecutive).
#pragma unroll
  for (int nj = 0; nj < 2; ++nj) {
    int v = nj * 16 + l15;
    if (v < 25) {
      size_t rowbase = (((size_t)(n * TT + t) * VV + v)) * 128 + wid * 32;
#pragma unroll
      for (int mi = 0; mi < 2; ++mi) {
        int ob = mi * 16 + (l4 << 2);
        int og = wid * 32 + ob;
        float4 gg = *(const float4*)&g_out[og];
        float4 vv = *(const float4*)&v_out[og];
        float4 mm = *(const float4*)&m_out[og];
        float4 be = *(const float4*)&beta_out[og];
        float4 bo = *(const float4*)&b_out[og];
        float4 xv = *(const float4*)&x[rowbase + ob];
        float4 r;
        float s1, a;
        s1 = gg.x * rsqrtf(vv.x + EPSF);
        a = (acc[mi][nj][0] + bo.x) * s1 + (be.x - mm.x * s1) + xv.x;
        r.x = a > 0.f ? a : 0.1f * a;
        s1 = gg.y * rsqrtf(vv.y + EPSF);
        a = (acc[mi][nj][1] + bo.y) * s1 + (be.y - mm.y * s1) + xv.y;
        r.y = a > 0.f ? a : 0.1f * a;
        s1 = gg.z * rsqrtf(vv.z + EPSF);
        a = (acc[mi][nj][2] + bo.z) * s1 + (be.z - mm.z * s1) + xv.z;
        r.z = a > 0.f ? a : 0.1f * a;
        s1 = gg.w * rsqrtf(vv.w + EPSF);
        a = (acc[mi][nj][3] + bo.w) * s1 + (be.w - mm.w * s1) + xv.w;
        r.w = a > 0.f ? a : 0.1f * a;
        *(float4*)&y1[rowbase + ob] = r;
      }
    }
  }
}

// ---------------- K4: ff conv as bf16 MFMA GEMM + BN + leaky residual ----------------
__global__ __launch_bounds__(256) void k_ffg(
    const float* __restrict__ y1, const float* __restrict__ x,
    const ushort* __restrict__ wffb, const float* __restrict__ b_ff,
    const float* __restrict__ g_ff, const float* __restrict__ beta_ff,
    const float* __restrict__ m_ff, const float* __restrict__ v_ff,
    float* __restrict__ y2) {
  __shared__ __align__(16) ushort As[8][128][8];
  __shared__ __align__(16) ushort Bs[8][128][8];
  const int gm0 = blockIdx.x << 7;
  const int tid = threadIdx.x;
  const int lane = tid & 63, wid = tid >> 6;
  const int wm = wid >> 1, wn = wid & 1;
  const int srow = tid & 127;
  const int skg0 = tid >> 7;
  f32x4 acc[4][4] = {};
  for (int kh = 0; kh < 2; ++kh) {
    __syncthreads();
#pragma unroll
    for (int j = 0; j < 4; ++j) {
      int kg = skg0 + 2 * j;
      const float* yp = y1 + (((size_t)(gm0 + srow)) << 7) + kh * 64 + kg * 8;
      float4 a0 = *(const float4*)yp;
      float4 a1 = *(const float4*)(yp + 4);
      uint4 pk;
      pk.x = (uint)f2bf(a0.x) | ((uint)f2bf(a0.y) << 16);
      pk.y = (uint)f2bf(a0.z) | ((uint)f2bf(a0.w) << 16);
      pk.z = (uint)f2bf(a1.x) | ((uint)f2bf(a1.y) << 16);
      pk.w = (uint)f2bf(a1.z) | ((uint)f2bf(a1.w) << 16);
      *(uint4*)&As[kg][srow][0] = pk;
      *(uint4*)&Bs[kg][srow][0] =
          *(const uint4*)&wffb[(srow << 7) + kh * 64 + kg * 8];
    }
    __syncthreads();
#pragma unroll
    for (int ks = 0; ks < 2; ++ks) {
      int g = ks * 4 + (lane >> 4);
      bf16x8 af[4], bfr[4];
#pragma unroll
      for (int mi = 0; mi < 4; ++mi)
        af[mi] = *(const bf16x8*)&As[g][wm * 64 + mi * 16 + (lane & 15)][0];
#pragma unroll
      for (int ni = 0; ni < 4; ++ni)
        bfr[ni] = *(const bf16x8*)&Bs[g][wn * 64 + ni * 16 + (lane & 15)][0];
#pragma unroll
      for (int mi = 0; mi < 4; ++mi)
#pragma unroll
        for (int ni = 0; ni < 4; ++ni)
          acc[mi][ni] = __builtin_amdgcn_mfma_f32_16x16x32_bf16(
              af[mi], bfr[ni], acc[mi][ni], 0, 0, 0);
    }
  }
  const int l15 = lane & 15, l4 = lane >> 4;
#pragma unroll
  for (int ni = 0; ni < 4; ++ni) {
    int o = wn * 64 + ni * 16 + l15;
    float s1 = g_ff[o] * rsqrtf(v_ff[o] + EPSF);
    float sh = beta_ff[o] - m_ff[o] * s1;
    float bb = b_ff[o];
#pragma unroll
    for (int mi = 0; mi < 4; ++mi) {
#pragma unroll
      for (int reg = 0; reg < 4; ++reg) {
        int row = gm0 + wm * 64 + mi * 16 + (l4 << 2) + reg;
        size_t idx = ((size_t)row << 7) + o;
        float a = (acc[mi][ni][reg] + bb) * s1 + sh;
        float rr = x[idx] + a;
        y2[idx] = rr > 0.f ? rr : 0.1f * rr;
      }
    }
  }
}

// ---------------- K5a: w_t (o,c,kt) -> bf16 wbt[o][kt*128+c] ----------------
__global__ __launch_bounds__(256) void k_wtb(const float* __restrict__ w_t,
                                             ushort* __restrict__ wbt) {
  int i = blockIdx.x * 256 + threadIdx.x;
  if (i < 128 * 128 * 7) {
    int o = i / 896;
    int rem = i - o * 896;
    int c = rem / 7, kt = rem - c * 7;
    wbt[o * 896 + kt * 128 + c] = f2bf(w_t[i]);
  }
}

// ---------------- K5: temporal conv as bf16 MFMA GEMM ----------------
__global__ __launch_bounds__(256, 2) void k_tconv(
    const float* __restrict__ y2, const float* __restrict__ x,
    const ushort* __restrict__ wbt, const float* __restrict__ b_t,
    const float* __restrict__ g_t, const float* __restrict__ beta_t,
    const float* __restrict__ m_t, const float* __restrict__ v_t,
    float* __restrict__ out) {
  __shared__ __align__(16) uint4 As[280 * 16];  // [row][16B-chunk], ^(row&7)
  const int n = blockIdx.y;
  const int r0 = blockIdx.x << 7;
  const int tid = threadIdx.x;
  const float* y2n = y2 + ((size_t)n * 7200 << 7);
  for (int i = tid; i < 278 * 16; i += 256) {
    int rl = i >> 4, cc = i & 15;
    int g = r0 - 75 + rl;
    uint4 pk = make_uint4(0u, 0u, 0u, 0u);
    if (g >= 0 && g < 7200) {
      const float* xp = y2n + ((size_t)g << 7) + (cc << 3);
      float4 a0 = *(const float4*)xp;
      float4 a1 = *(const float4*)(xp + 4);
      pk.x = (uint)f2bf(a0.x) | ((uint)f2bf(a0.y) << 16);
      pk.y = (uint)f2bf(a0.z) | ((uint)f2bf(a0.w) << 16);
      pk.z = (uint)f2bf(a1.x) | ((uint)f2bf(a1.y) << 16);
      pk.w = (uint)f2bf(a1.z) | ((uint)f2bf(a1.w) << 16);
    }
    As[(rl << 4) + (cc ^ (rl & 7))] = pk;
  }
  __syncthreads();
  const int lane = tid & 63, wid = tid >> 6;
  const int wm = wid >> 1, wn = wid & 1;
  const int l15 = lane & 15, l4 = lane >> 4;
  f32x4 acc[4][4] = {};
  for (int kt = 0; kt < 7; ++kt) {
    bf16x8 bfr[4][4];
#pragma unroll
    for (int ni = 0; ni < 4; ++ni) {
      const ushort* bp =
          wbt + (size_t)(wn * 64 + ni * 16 + l15) * 896 + kt * 128 + l4 * 8;
#pragma unroll
      for (int cc0 = 0; cc0 < 4; ++cc0)
        bfr[ni][cc0] = *(const bf16x8*)(bp + cc0 * 32);
    }
#pragma unroll
    for (int cc0 = 0; cc0 < 4; ++cc0) {
      bf16x8 af[4];
#pragma unroll
      for (int mi = 0; mi < 4; ++mi) {
        int rl = wm * 64 + mi * 16 + l15 + 25 * kt;
        af[mi] = *(const bf16x8*)&As[(rl << 4) + ((cc0 * 4 + l4) ^ (rl & 7))];
      }
#pragma unroll
      for (int mi = 0; mi < 4; ++mi)
#pragma unroll
        for (int ni = 0; ni < 4; ++ni)
          acc[mi][ni] = __builtin_amdgcn_mfma_f32_16x16x32_bf16(
              af[mi], bfr[ni][cc0], acc[mi][ni], 0, 0, 0);
    }
  }
#pragma unroll
  for (int ni = 0; ni < 4; ++ni) {
    int o = wn * 64 + ni * 16 + l15;
    float s1 = g_t[o] * rsqrtf(v_t[o] + EPSF);
    float sh = beta_t[o] - m_t[o] * s1;
    float bb = b_t[o];
#pragma unroll
    for (int mi = 0; mi < 4; ++mi) {
#pragma unroll
      for (int reg = 0; reg < 4; ++reg) {
        int grow = r0 + wm * 64 + mi * 16 + (l4 << 2) + reg;
        if (grow < 7200) {
          size_t idx = (((size_t)n * 7200 + grow) << 7) + o;
          float z = (acc[mi][ni][reg] + bb) * s1 + sh;
          z += y2[idx];
          z = z > 0.f ? z : 0.1f * z;
          z += x[idx];
          out[idx] = z > 0.f ? z : 0.f;
        }
      }
    }
  }
}

extern "C" void kernel_launch(void* const* d_in, const int* in_sizes, int n_in,
                              void* d_out, int out_size, void* d_ws, size_t ws_size,
                              hipStream_t stream) {
  const float* x      = (const float*)d_in[0];
  const float* w_k    = (const float*)d_in[1];
  const float* b_k    = (const float*)d_in[2];
  const float* w_q    = (const float*)d_in[3];
  const float* b_q    = (const float*)d_in[4];
  const float* alphas = (const float*)d_in[5];
  const float* att0   = (const float*)d_in[6];
  const float* w_out  = (const float*)d_in[7];
  const float* b_out  = (const float*)d_in[8];
  const float* g_out  = (const float*)d_in[9];
  const float* be_out = (const float*)d_in[10];
  const float* m_out  = (const float*)d_in[11];
  const float* v_out  = (const float*)d_in[12];
  const float* w_ff   = (const float*)d_in[13];
  const float* b_ff   = (const float*)d_in[14];
  const float* g_ff   = (const float*)d_in[15];
  const float* be_ff  = (const float*)d_in[16];
  const float* m_ff   = (const float*)d_in[17];
  const float* v_ff   = (const float*)d_in[18];
  const float* w_t    = (const float*)d_in[19];
  const float* b_t    = (const float*)d_in[20];
  const float* g_t    = (const float*)d_in[21];
  const float* be_t   = (const float*)d_in[22];
  const float* m_t    = (const float*)d_in[23];
  const float* v_t    = (const float*)d_in[24];

  float* ws = (float*)d_ws;
  // Region plan (floats), total 32,108,288 = round-1 proven footprint:
  float* qfull = ws;               // [0, 14848000)   qb bf16 -> Hc bf16 -> y2
  float* kfull = ws + 14848000;    // [.., +14745600) kb bf16 -> y1
  float* part  = ws + 29593600;    // [.., +2160000)  wb/wkqb/wffb bf16
  float* attr  = ws + 31753600;    // [.., +240000)   attTb bf16 (307200 sh)
  float* wtr   = ws + 31993600;    // [.., +114688)   wbt bf16
  ushort* qbb   = (ushort*)qfull;
  ushort* kbb   = (ushort*)kfull;
  ushort* Hc    = (ushort*)qfull;  // 4n chunk: 4*288*128*200 = 29,491,200 sh
  ushort* wb    = (ushort*)part;            // 131072 shorts
  ushort* wkqb  = (ushort*)part + 131072;   //  32768 shorts
  ushort* wffb  = (ushort*)part + 163840;   //  16384 shorts
  ushort* attTb = (ushort*)attr;
  ushort* wbt   = (ushort*)wtr;
  float* y1 = kfull;
  float* y2 = qfull;
  float* outp = (float*)d_out;

  k_wcvt<<<704, 256, 0, stream>>>(w_out, w_k, w_q, w_ff, wb, wkqb, wffb);
  k_qkg<<<dim3(900, 2), 256, 0, stream>>>(x, wkqb, b_k, b_q, kbb, qbb);
  k_qkpad<<<400, 256, 0, stream>>>(b_q, qbb);
  k_scores<<<128, 512, 0, stream>>>(kbb, qbb, alphas, att0, attTb);
  for (int n0 = 0; n0 < 16; n0 += 4) {
    k_hgemm<<<1800, 256, 0, stream>>>(x, wb, Hc, n0);
    k_apply<<<dim3(288, 4), 256, 0, stream>>>(Hc, attTb, x, b_out, g_out,
                                              be_out, m_out, v_out, y1, n0);
  }
  k_ffg<<<900, 256, 0, stream>>>(y1, x, wffb, b_ff, g_ff, be_ff, m_ff, v_ff, y2);
  k_wtb<<<448, 256, 0, stream>>>(w_t, wbt);
  k_tconv<<<dim3(57, 16), 256, 0, stream>>>(y2, x, wbt, b_t, g_t, be_t, m_t,
                                            v_t, outp);
}

// Round 11
// 517.318 us; speedup vs baseline: 2.2203x; 2.2203x over previous
//
#include <hip/hip_runtime.h>

// SSHA block. Round 11 = round 9 flow (H'' path reverted — its scatter write
// amplified 10x) with k_attn3 occupancy fix: Av LDS copy deleted, attention
// A-fragments read directly from L2-resident attTb. LDS 77->35 KB => 4
// blocks/CU (16 waves). Everything else identical to round 9.
// Shapes: N=16, T=288, V=25, C=128, S=8, IC=16, W=3, U=75, TP=290.

#define NN 16
#define TT 288
#define VV 25
#define CC 128
#define SS 8
#define UU 75
#define TP 290
#define EPSF 1e-5f

typedef __attribute__((ext_vector_type(8))) short bf16x8;
typedef __attribute__((ext_vector_type(4))) float f32x4;

static __device__ __forceinline__ ushort f2bf(float f) {
  uint u = __float_as_uint(f);
  u = (u + 0x7FFFu + ((u >> 16) & 1u)) >> 16;
  return (ushort)u;
}

// ---------------- K0: weight converts ----------------
__global__ __launch_bounds__(256) void k_wcvt(
    const float* __restrict__ w_out, const float* __restrict__ w_k,
    const float* __restrict__ w_q, const float* __restrict__ w_ff,
    ushort* __restrict__ wb, ushort* __restrict__ wkqb,
    ushort* __restrict__ wffb) {
  int i = blockIdx.x * 256 + threadIdx.x;  // 180224 total
  if (i < 131072) {
    int j = i >> 7, c = i & 127;
    int s = j >> 7, o = j & 127;
    wb[i] = f2bf(w_out[(o << 10) + (s << 7) + c]);
  } else {
    int j = i - 131072;
    if (j < 16384) wkqb[j] = f2bf(w_k[j]);
    else if (j < 32768) wkqb[j] = f2bf(w_q[j - 16384]);
    else wffb[j - 32768] = f2bf(w_ff[j - 32768]);
  }
}

// ---------------- K1: k/q 1x1 convs as bf16 MFMA GEMM ----------------
__global__ __launch_bounds__(256) void k_qkg(
    const float* __restrict__ x, const ushort* __restrict__ wkqb,
    const float* __restrict__ b_k, const float* __restrict__ b_q,
    ushort* __restrict__ kb, ushort* __restrict__ qb) {
  __shared__ __align__(16) ushort As[8][128][8];
  __shared__ __align__(16) ushort Bs[8][128][8];
  const int bm = blockIdx.x, by = blockIdx.y;
  const int gm0 = bm << 7;
  const int tid = threadIdx.x;
  const int lane = tid & 63, wid = tid >> 6;
  const int wm = wid >> 1, wn = wid & 1;
  const int srow = tid & 127;
  const int skg0 = tid >> 7;
  const ushort* wsrc = wkqb + by * 16384;
  f32x4 acc[4][4] = {};
  for (int kh = 0; kh < 2; ++kh) {
    __syncthreads();
#pragma unroll
    for (int j = 0; j < 4; ++j) {
      int kg = skg0 + 2 * j;
      const float* xp = x + (((size_t)(gm0 + srow)) << 7) + kh * 64 + kg * 8;
      float4 a0 = *(const float4*)xp;
      float4 a1 = *(const float4*)(xp + 4);
      uint4 pk;
      pk.x = (uint)f2bf(a0.x) | ((uint)f2bf(a0.y) << 16);
      pk.y = (uint)f2bf(a0.z) | ((uint)f2bf(a0.w) << 16);
      pk.z = (uint)f2bf(a1.x) | ((uint)f2bf(a1.y) << 16);
      pk.w = (uint)f2bf(a1.z) | ((uint)f2bf(a1.w) << 16);
      *(uint4*)&As[kg][srow][0] = pk;
      *(uint4*)&Bs[kg][srow][0] =
          *(const uint4*)&wsrc[(srow << 7) + kh * 64 + kg * 8];
    }
    __syncthreads();
#pragma unroll
    for (int ks = 0; ks < 2; ++ks) {
      int g = ks * 4 + (lane >> 4);
      bf16x8 af[4], bfr[4];
#pragma unroll
      for (int mi = 0; mi < 4; ++mi)
        af[mi] = *(const bf16x8*)&As[g][wm * 64 + mi * 16 + (lane & 15)][0];
#pragma unroll
      for (int ni = 0; ni < 4; ++ni)
        bfr[ni] = *(const bf16x8*)&Bs[g][wn * 64 + ni * 16 + (lane & 15)][0];
#pragma unroll
      for (int mi = 0; mi < 4; ++mi)
#pragma unroll
        for (int ni = 0; ni < 4; ++ni)
          acc[mi][ni] = __builtin_amdgcn_mfma_f32_16x16x32_bf16(
              af[mi], bfr[ni], acc[mi][ni], 0, 0, 0);
    }
  }
  const int l15 = lane & 15, l4 = lane >> 4;
  const float* bias = by ? b_q : b_k;
#pragma unroll
  for (int ni = 0; ni < 4; ++ni) {
    int col = wn * 64 + ni * 16 + l15;
    float bb = bias[col];
#pragma unroll
    for (int mi = 0; mi < 4; ++mi) {
#pragma unroll
      for (int reg = 0; reg < 4; ++reg) {
        int row = gm0 + wm * 64 + mi * 16 + (l4 << 2) + reg;
        ushort val = f2bf(acc[mi][ni][reg] + bb);
        if (by == 0) {
          kb[((size_t)row << 7) + col] = val;
        } else {
          int n = row / 7200;
          qb[((size_t)(row + n * 50 + 25) << 7) + col] = val;
        }
      }
    }
  }
}

// qb pad rows (tp=0, tp=289): bias-only.
__global__ __launch_bounds__(256) void k_qkpad(const float* __restrict__ b_q,
                                               ushort* __restrict__ qb) {
  int i = blockIdx.x * 256 + threadIdx.x;  // 16*2*25*128
  int o = i & 127;
  int r = i >> 7;
  int v = r % 25;
  int e = (r / 25) & 1;
  int n = r / 50;
  int tp = e ? 289 : 0;
  qb[((size_t)((n * TP + tp) * VV + v) << 7) + o] = f2bf(b_q[o]);
}

// ---------------- K2: scores (bf16 MFMA) + fused softmax -> attTb bf16 ----------------
// attTb[n][s][v(25)][u(104)]: att^T, zero-padded u>=75.
__global__ __launch_bounds__(512) void k_scores(
    const ushort* __restrict__ kb, const ushort* __restrict__ qb,
    const float* __restrict__ alphas, const float* __restrict__ att0,
    ushort* __restrict__ attTb) {
  __shared__ float red[8][2640];  // [wave][u(80) * 33 + v(32)]
  __shared__ float scl[1875];
  __shared__ float mx[25];
  __shared__ float den[25];
  const int bx = blockIdx.x;
  const int n = bx >> 3, s = bx & 7;
  const int tid = threadIdx.x;
  const int lane = tid & 63, wid = tid >> 6;
  const int l15 = lane & 15, l4 = lane >> 4;
  const int dt = l4 >> 1;
  const int sic = s * 16 + (l4 & 1) * 8;
  int qoff[5];
#pragma unroll
  for (int tu = 0; tu < 5; ++tu) {
    int u = tu * 16 + l15;
    int w = u / 25, vp = u - w * 25;
    qoff[tu] = (w * 25 + vp) * 128 + sic;
  }
  const bool qv4 = (64 + l15) < 75;
  const bool kv1 = (16 + l15) < 25;
  int koff0 = l15 * 128 + sic;
  int koff1 = (16 + l15) * 128 + sic;
  const ushort* qbase = qb + (size_t)n * 928000 + (size_t)dt * 3200;
  const ushort* kbase = kb + (size_t)n * 921600 + (size_t)dt * 3200;
  f32x4 acc[5][2] = {};
  const bf16x8 zf = {};
  for (int kk = wid; kk < 144; kk += 8) {
    const ushort* qp = qbase + kk * 6400;
    const ushort* kp = kbase + kk * 6400;
    bf16x8 a[5], b[2];
#pragma unroll
    for (int tu = 0; tu < 4; ++tu) a[tu] = *(const bf16x8*)(qp + qoff[tu]);
    a[4] = qv4 ? *(const bf16x8*)(qp + qoff[4]) : zf;
    b[0] = *(const bf16x8*)(kp + koff0);
    b[1] = kv1 ? *(const bf16x8*)(kp + koff1) : zf;
#pragma unroll
    for (int tu = 0; tu < 5; ++tu)
#pragma unroll
      for (int tv = 0; tv < 2; ++tv)
        acc[tu][tv] = __builtin_amdgcn_mfma_f32_16x16x32_bf16(
            a[tu], b[tv], acc[tu][tv], 0, 0, 0);
  }
#pragma unroll
  for (int tu = 0; tu < 5; ++tu)
#pragma unroll
    for (int tv = 0; tv < 2; ++tv) {
#pragma unroll
      for (int reg = 0; reg < 4; ++reg)
        red[wid][(tu * 16 + l4 * 4 + reg) * 33 + tv * 16 + l15] =
            acc[tu][tv][reg];
    }
  __syncthreads();
  const float inv = 1.0f / 4608.0f;
  for (int i = tid; i < 1875; i += 512) {
    int u = i / 25, v = i - u * 25;
    float a = 0.f;
#pragma unroll
    for (int w = 0; w < 8; ++w) a += red[w][u * 33 + v];
    scl[i] = a * inv;
  }
  __syncthreads();
  if (tid < 25) {
    float m = -1e30f;
    for (int u = 0; u < 75; ++u) m = fmaxf(m, scl[u * 25 + tid]);
    float d = 0.f;
    for (int u = 0; u < 75; ++u) d += expf(scl[u * 25 + tid] - m);
    mx[tid] = m;
    den[tid] = d;
  }
  __syncthreads();
  const float alpha = alphas[s];
  ushort* op = attTb + (size_t)bx * 2600;
  for (int i = tid; i < 2600; i += 512) {
    int v = i / 104, u = i - v * 104;
    float val = 0.f;
    if (u < 75)
      val = expf(scl[u * 25 + v] - mx[v]) / den[v] * alpha +
            att0[(s * 75 + u) * 25 + v];
    op[i] = f2bf(val);
  }
}

// ---------------- K3: attention-apply + out conv (double MFMA) ----------------
// Grid (288, 16), 256 thr = 4 waves. Wave wid owns c-range (step1) and
// o-range (step2) [wid*32, wid*32+32). A-frags read direct from L2 attTb.
__global__ __launch_bounds__(256, 4) void k_attn3(
    const float* __restrict__ x, const ushort* __restrict__ attTb,
    const ushort* __restrict__ wb, const float* __restrict__ b_out,
    const float* __restrict__ g_out, const float* __restrict__ beta_out,
    const float* __restrict__ m_out, const float* __restrict__ v_out,
    float* __restrict__ y1) {
  __shared__ __align__(16) ushort Xt[128 * 104];  // [c][u], zero-pad u>=75
  __shared__ __align__(16) ushort Yl[32 * 136];   // [v][c] bf16 roundtrip
  const int t = blockIdx.x, n = blockIdx.y;
  const int tid = threadIdx.x;
  // stage Xt[c][u]: u = w*25+vp -> x row (n, t+w-1, vp)
  for (int i = tid; i < 128 * 104; i += 256) {
    int u = i >> 7, c = i & 127;
    float val = 0.f;
    if (u < 75) {
      int w = u / 25, vp = u - w * 25;
      int tr = t + w - 1;
      if (tr >= 0 && tr < TT)
        val = x[(((size_t)(n * TT + tr) * VV + vp)) * 128 + c];
    }
    Xt[c * 104 + u] = f2bf(val);
  }
  __syncthreads();
  const int lane = tid & 63, wid = tid >> 6;
  const int l15 = lane & 15, l4 = lane >> 4;
  const bf16x8 zf = {};
  f32x4 accO[2][2] = {};  // [mi(o)][nj(v)]
  const ushort* Avn = attTb + (size_t)n * 20800;
  for (int s = 0; s < 8; ++s) {
    // ---- step 1: Y_s[v, c] for this wave's c-range ----
    f32x4 accY[2][2] = {};  // [mi(v)][nj(c)]
    const ushort* AvS = Avn + s * 2600;
#pragma unroll
    for (int ks = 0; ks < 3; ++ks) {
      int u0 = ks * 32 + l4 * 8;
      bf16x8 av0 = *(const bf16x8*)&AvS[l15 * 104 + u0];
      int r1 = 16 + l15;
      bf16x8 av1 = *(const bf16x8*)&AvS[(r1 <= 24 ? r1 : 24) * 104 + u0];
      if (l15 > 8) av1 = zf;  // v >= 25 -> zero row
      bf16x8 xb0 = *(const bf16x8*)&Xt[(wid * 32 + l15) * 104 + u0];
      bf16x8 xb1 = *(const bf16x8*)&Xt[(wid * 32 + 16 + l15) * 104 + u0];
      accY[0][0] = __builtin_amdgcn_mfma_f32_16x16x32_bf16(av0, xb0, accY[0][0], 0, 0, 0);
      accY[0][1] = __builtin_amdgcn_mfma_f32_16x16x32_bf16(av0, xb1, accY[0][1], 0, 0, 0);
      accY[1][0] = __builtin_amdgcn_mfma_f32_16x16x32_bf16(av1, xb0, accY[1][0], 0, 0, 0);
      accY[1][1] = __builtin_amdgcn_mfma_f32_16x16x32_bf16(av1, xb1, accY[1][1], 0, 0, 0);
    }
    __syncthreads();  // previous step-2 readers done with Yl
#pragma unroll
    for (int mi = 0; mi < 2; ++mi)
#pragma unroll
      for (int nj = 0; nj < 2; ++nj)
#pragma unroll
        for (int reg = 0; reg < 4; ++reg)
          Yl[(mi * 16 + l4 * 4 + reg) * 136 + wid * 32 + nj * 16 + l15] =
              f2bf(accY[mi][nj][reg]);
    __syncthreads();
    // ---- step 2: O[o, v] += W_s . Y_s for this wave's o-range ----
    const ushort* wS = wb + s * 16384;
#pragma unroll
    for (int kc = 0; kc < 4; ++kc) {
      int c0 = kc * 32 + l4 * 8;
      bf16x8 wf0 = *(const bf16x8*)&wS[(wid * 32 + l15) * 128 + c0];
      bf16x8 wf1 = *(const bf16x8*)&wS[(wid * 32 + 16 + l15) * 128 + c0];
      bf16x8 yb0 = *(const bf16x8*)&Yl[l15 * 136 + c0];
      bf16x8 yb1 = *(const bf16x8*)&Yl[(16 + l15) * 136 + c0];
      accO[0][0] = __builtin_amdgcn_mfma_f32_16x16x32_bf16(wf0, yb0, accO[0][0], 0, 0, 0);
      accO[0][1] = __builtin_amdgcn_mfma_f32_16x16x32_bf16(wf0, yb1, accO[0][1], 0, 0, 0);
      accO[1][0] = __builtin_amdgcn_mfma_f32_16x16x32_bf16(wf1, yb0, accO[1][0], 0, 0, 0);
      accO[1][1] = __builtin_amdgcn_mfma_f32_16x16x32_bf16(wf1, yb1, accO[1][1], 0, 0, 0);
    }
  }
  // ---- epilogue: BN + leaky(x + .) ----
#pragma unroll
  for (int nj = 0; nj < 2; ++nj) {
    int v = nj * 16 + l15;
    if (v < 25) {
      size_t rowbase = (((size_t)(n * TT + t) * VV + v)) * 128 + wid * 32;
#pragma unroll
      for (int mi = 0; mi < 2; ++mi) {
        int ob = mi * 16 + (l4 << 2);  // o offset within wave range
        int og = wid * 32 + ob;
        float4 gg = *(const float4*)&g_out[og];
        float4 vv = *(const float4*)&v_out[og];
        float4 mm = *(const float4*)&m_out[og];
        float4 be = *(const float4*)&beta_out[og];
        float4 bo = *(const float4*)&b_out[og];
        float4 xv = *(const float4*)&x[rowbase + ob];
        float4 r;
        float s1, a;
        s1 = gg.x * rsqrtf(vv.x + EPSF);
        a = (accO[mi][nj][0] + bo.x) * s1 + (be.x - mm.x * s1) + xv.x;
        r.x = a > 0.f ? a : 0.1f * a;
        s1 = gg.y * rsqrtf(vv.y + EPSF);
        a = (accO[mi][nj][1] + bo.y) * s1 + (be.y - mm.y * s1) + xv.y;
        r.y = a > 0.f ? a : 0.1f * a;
        s1 = gg.z * rsqrtf(vv.z + EPSF);
        a = (accO[mi][nj][2] + bo.z) * s1 + (be.z - mm.z * s1) + xv.z;
        r.z = a > 0.f ? a : 0.1f * a;
        s1 = gg.w * rsqrtf(vv.w + EPSF);
        a = (accO[mi][nj][3] + bo.w) * s1 + (be.w - mm.w * s1) + xv.w;
        r.w = a > 0.f ? a : 0.1f * a;
        *(float4*)&y1[rowbase + ob] = r;
      }
    }
  }
}

// ---------------- K4: ff conv as bf16 MFMA GEMM + BN + leaky residual ----------------
__global__ __launch_bounds__(256) void k_ffg(
    const float* __restrict__ y1, const float* __restrict__ x,
    const ushort* __restrict__ wffb, const float* __restrict__ b_ff,
    const float* __restrict__ g_ff, const float* __restrict__ beta_ff,
    const float* __restrict__ m_ff, const float* __restrict__ v_ff,
    float* __restrict__ y2) {
  __shared__ __align__(16) ushort As[8][128][8];
  __shared__ __align__(16) ushort Bs[8][128][8];
  const int gm0 = blockIdx.x << 7;
  const int tid = threadIdx.x;
  const int lane = tid & 63, wid = tid >> 6;
  const int wm = wid >> 1, wn = wid & 1;
  const int srow = tid & 127;
  const int skg0 = tid >> 7;
  f32x4 acc[4][4] = {};
  for (int kh = 0; kh < 2; ++kh) {
    __syncthreads();
#pragma unroll
    for (int j = 0; j < 4; ++j) {
      int kg = skg0 + 2 * j;
      const float* yp = y1 + (((size_t)(gm0 + srow)) << 7) + kh * 64 + kg * 8;
      float4 a0 = *(const float4*)yp;
      float4 a1 = *(const float4*)(yp + 4);
      uint4 pk;
      pk.x = (uint)f2bf(a0.x) | ((uint)f2bf(a0.y) << 16);
      pk.y = (uint)f2bf(a0.z) | ((uint)f2bf(a0.w) << 16);
      pk.z = (uint)f2bf(a1.x) | ((uint)f2bf(a1.y) << 16);
      pk.w = (uint)f2bf(a1.z) | ((uint)f2bf(a1.w) << 16);
      *(uint4*)&As[kg][srow][0] = pk;
      *(uint4*)&Bs[kg][srow][0] =
          *(const uint4*)&wffb[(srow << 7) + kh * 64 + kg * 8];
    }
    __syncthreads();
#pragma unroll
    for (int ks = 0; ks < 2; ++ks) {
      int g = ks * 4 + (lane >> 4);
      bf16x8 af[4], bfr[4];
#pragma unroll
      for (int mi = 0; mi < 4; ++mi)
        af[mi] = *(const bf16x8*)&As[g][wm * 64 + mi * 16 + (lane & 15)][0];
#pragma unroll
      for (int ni = 0; ni < 4; ++ni)
        bfr[ni] = *(const bf16x8*)&Bs[g][wn * 64 + ni * 16 + (lane & 15)][0];
#pragma unroll
      for (int mi = 0; mi < 4; ++mi)
#pragma unroll
        for (int ni = 0; ni < 4; ++ni)
          acc[mi][ni] = __builtin_amdgcn_mfma_f32_16x16x32_bf16(
              af[mi], bfr[ni], acc[mi][ni], 0, 0, 0);
    }
  }
  const int l15 = lane & 15, l4 = lane >> 4;
#pragma unroll
  for (int ni = 0; ni < 4; ++ni) {
    int o = wn * 64 + ni * 16 + l15;
    float s1 = g_ff[o] * rsqrtf(v_ff[o] + EPSF);
    float sh = beta_ff[o] - m_ff[o] * s1;
    float bb = b_ff[o];
#pragma unroll
    for (int mi = 0; mi < 4; ++mi) {
#pragma unroll
      for (int reg = 0; reg < 4; ++reg) {
        int row = gm0 + wm * 64 + mi * 16 + (l4 << 2) + reg;
        size_t idx = ((size_t)row << 7) + o;
        float a = (acc[mi][ni][reg] + bb) * s1 + sh;
        float rr = x[idx] + a;
        y2[idx] = rr > 0.f ? rr : 0.1f * rr;
      }
    }
  }
}

// ---------------- K5a: w_t (o,c,kt) -> bf16 wbt[o][kt*128+c] ----------------
__global__ __launch_bounds__(256) void k_wtb(const float* __restrict__ w_t,
                                             ushort* __restrict__ wbt) {
  int i = blockIdx.x * 256 + threadIdx.x;
  if (i < 128 * 128 * 7) {
    int o = i / 896;
    int rem = i - o * 896;
    int c = rem / 7, kt = rem - c * 7;
    wbt[o * 896 + kt * 128 + c] = f2bf(w_t[i]);
  }
}

// ---------------- K5: temporal conv as bf16 MFMA GEMM ----------------
__global__ __launch_bounds__(256, 2) void k_tconv(
    const float* __restrict__ y2, const float* __restrict__ x,
    const ushort* __restrict__ wbt, const float* __restrict__ b_t,
    const float* __restrict__ g_t, const float* __restrict__ beta_t,
    const float* __restrict__ m_t, const float* __restrict__ v_t,
    float* __restrict__ out) {
  __shared__ __align__(16) uint4 As[280 * 16];  // [row][16B-chunk], ^(row&7)
  const int n = blockIdx.y;
  const int r0 = blockIdx.x << 7;
  const int tid = threadIdx.x;
  const float* y2n = y2 + ((size_t)n * 7200 << 7);
  for (int i = tid; i < 278 * 16; i += 256) {
    int rl = i >> 4, cc = i & 15;
    int g = r0 - 75 + rl;
    uint4 pk = make_uint4(0u, 0u, 0u, 0u);
    if (g >= 0 && g < 7200) {
      const float* xp = y2n + ((size_t)g << 7) + (cc << 3);
      float4 a0 = *(const float4*)xp;
      float4 a1 = *(const float4*)(xp + 4);
      pk.x = (uint)f2bf(a0.x) | ((uint)f2bf(a0.y) << 16);
      pk.y = (uint)f2bf(a0.z) | ((uint)f2bf(a0.w) << 16);
      pk.z = (uint)f2bf(a1.x) | ((uint)f2bf(a1.y) << 16);
      pk.w = (uint)f2bf(a1.z) | ((uint)f2bf(a1.w) << 16);
    }
    As[(rl << 4) + (cc ^ (rl & 7))] = pk;
  }
  __syncthreads();
  const int lane = tid & 63, wid = tid >> 6;
  const int wm = wid >> 1, wn = wid & 1;
  const int l15 = lane & 15, l4 = lane >> 4;
  f32x4 acc[4][4] = {};
  for (int kt = 0; kt < 7; ++kt) {
    bf16x8 bfr[4][4];
#pragma unroll
    for (int ni = 0; ni < 4; ++ni) {
      const ushort* bp =
          wbt + (size_t)(wn * 64 + ni * 16 + l15) * 896 + kt * 128 + l4 * 8;
#pragma unroll
      for (int cc0 = 0; cc0 < 4; ++cc0)
        bfr[ni][cc0] = *(const bf16x8*)(bp + cc0 * 32);
    }
#pragma unroll
    for (int cc0 = 0; cc0 < 4; ++cc0) {
      bf16x8 af[4];
#pragma unroll
      for (int mi = 0; mi < 4; ++mi) {
        int rl = wm * 64 + mi * 16 + l15 + 25 * kt;
        af[mi] = *(const bf16x8*)&As[(rl << 4) + ((cc0 * 4 + l4) ^ (rl & 7))];
      }
#pragma unroll
      for (int mi = 0; mi < 4; ++mi)
#pragma unroll
        for (int ni = 0; ni < 4; ++ni)
          acc[mi][ni] = __builtin_amdgcn_mfma_f32_16x16x32_bf16(
              af[mi], bfr[ni][cc0], acc[mi][ni], 0, 0, 0);
    }
  }
#pragma unroll
  for (int ni = 0; ni < 4; ++ni) {
    int o = wn * 64 + ni * 16 + l15;
    float s1 = g_t[o] * rsqrtf(v_t[o] + EPSF);
    float sh = beta_t[o] - m_t[o] * s1;
    float bb = b_t[o];
#pragma unroll
    for (int mi = 0; mi < 4; ++mi) {
#pragma unroll
      for (int reg = 0; reg < 4; ++reg) {
        int grow = r0 + wm * 64 + mi * 16 + (l4 << 2) + reg;
        if (grow < 7200) {
          size_t idx = (((size_t)n * 7200 + grow) << 7) + o;
          float z = (acc[mi][ni][reg] + bb) * s1 + sh;
          z += y2[idx];
          z = z > 0.f ? z : 0.1f * z;
          z += x[idx];
          out[idx] = z > 0.f ? z : 0.f;
        }
      }
    }
  }
}

extern "C" void kernel_launch(void* const* d_in, const int* in_sizes, int n_in,
                              void* d_out, int out_size, void* d_ws, size_t ws_size,
                              hipStream_t stream) {
  const float* x      = (const float*)d_in[0];
  const float* w_k    = (const float*)d_in[1];
  const float* b_k    = (const float*)d_in[2];
  const float* w_q    = (const float*)d_in[3];
  const float* b_q    = (const float*)d_in[4];
  const float* alphas = (const float*)d_in[5];
  const float* att0   = (const float*)d_in[6];
  const float* w_out  = (const float*)d_in[7];
  const float* b_out  = (const float*)d_in[8];
  const float* g_out  = (const float*)d_in[9];
  const float* be_out = (const float*)d_in[10];
  const float* m_out  = (const float*)d_in[11];
  const float* v_out  = (const float*)d_in[12];
  const float* w_ff   = (const float*)d_in[13];
  const float* b_ff   = (const float*)d_in[14];
  const float* g_ff   = (const float*)d_in[15];
  const float* be_ff  = (const float*)d_in[16];
  const float* m_ff   = (const float*)d_in[17];
  const float* v_ff   = (const float*)d_in[18];
  const float* w_t    = (const float*)d_in[19];
  const float* b_t    = (const float*)d_in[20];
  const float* g_t    = (const float*)d_in[21];
  const float* be_t   = (const float*)d_in[22];
  const float* m_t    = (const float*)d_in[23];
  const float* v_t    = (const float*)d_in[24];

  float* ws = (float*)d_ws;
  // Region plan (floats), total 32,108,288 = round-1 proven footprint:
  float* qfull = ws;               // [0, 14848000)   qb bf16 -> y2
  float* kfull = ws + 14848000;    // [.., +14745600) kb bf16 -> y1
  float* part  = ws + 29593600;    // [.., +2160000)  wb/wkqb/wffb bf16
  float* attr  = ws + 31753600;    // [.., +240000)   attTb bf16 (332800 sh)
  float* wtr   = ws + 31993600;    // [.., +114688)   wbt bf16
  ushort* qbb   = (ushort*)qfull;
  ushort* kbb   = (ushort*)kfull;
  ushort* wb    = (ushort*)part;            // 131072 shorts
  ushort* wkqb  = (ushort*)part + 131072;   //  32768 shorts
  ushort* wffb  = (ushort*)part + 163840;   //  16384 shorts
  ushort* attTb = (ushort*)attr;
  ushort* wbt   = (ushort*)wtr;
  float* y1 = kfull;
  float* y2 = qfull;
  float* outp = (float*)d_out;

  k_wcvt<<<704, 256, 0, stream>>>(w_out, w_k, w_q, w_ff, wb, wkqb, wffb);
  k_qkg<<<dim3(900, 2), 256, 0, stream>>>(x, wkqb, b_k, b_q, kbb, qbb);
  k_qkpad<<<400, 256, 0, stream>>>(b_q, qbb);
  k_scores<<<128, 512, 0, stream>>>(kbb, qbb, alphas, att0, attTb);
  k_attn3<<<dim3(288, 16), 256, 0, stream>>>(x, attTb, wb, b_out, g_out,
                                             be_out, m_out, v_out, y1);
  k_ffg<<<900, 256, 0, stream>>>(y1, x, wffb, b_ff, g_ff, be_ff, m_ff, v_ff, y2);
  k_wtb<<<448, 256, 0, stream>>>(w_t, wbt);
  k_tconv<<<dim3(57, 16), 256, 0, stream>>>(y2, x, wbt, b_t, g_t, be_t, m_t,
                                            v_t, outp);
}

// Round 12
// 400.492 us; speedup vs baseline: 2.8680x; 1.2917x over previous
//
#include <hip/hip_runtime.h>

// SSHA block. Round 12: k_attn3 TB=2 restructure with repacked u-axis.
//   u' = w*32+vp (zero-padded vp>=25) so each t's K-window starts 64B-aligned
//   at tt*32 in a SHARED staged slab: one block serves 2 t's from one Xt.
//   Xt staged vectorized (ds_write_b128) with chunk^(c&7) XOR swizzle.
//   k_scores emits attTb[n][s][v 25][u' 96]. Everything else = round 11.
// Shapes: N=16, T=288, V=25, C=128, S=8, IC=16, W=3, U=75, TP=290.

#define NN 16
#define TT 288
#define VV 25
#define CC 128
#define SS 8
#define UU 75
#define TP 290
#define EPSF 1e-5f

typedef __attribute__((ext_vector_type(8))) short bf16x8;
typedef __attribute__((ext_vector_type(4))) float f32x4;

static __device__ __forceinline__ ushort f2bf(float f) {
  uint u = __float_as_uint(f);
  u = (u + 0x7FFFu + ((u >> 16) & 1u)) >> 16;
  return (ushort)u;
}

// ---------------- K0: weight converts ----------------
__global__ __launch_bounds__(256) void k_wcvt(
    const float* __restrict__ w_out, const float* __restrict__ w_k,
    const float* __restrict__ w_q, const float* __restrict__ w_ff,
    ushort* __restrict__ wb, ushort* __restrict__ wkqb,
    ushort* __restrict__ wffb) {
  int i = blockIdx.x * 256 + threadIdx.x;  // 180224 total
  if (i < 131072) {
    int j = i >> 7, c = i & 127;
    int s = j >> 7, o = j & 127;
    wb[i] = f2bf(w_out[(o << 10) + (s << 7) + c]);
  } else {
    int j = i - 131072;
    if (j < 16384) wkqb[j] = f2bf(w_k[j]);
    else if (j < 32768) wkqb[j] = f2bf(w_q[j - 16384]);
    else wffb[j - 32768] = f2bf(w_ff[j - 32768]);
  }
}

// ---------------- K1: k/q 1x1 convs as bf16 MFMA GEMM ----------------
__global__ __launch_bounds__(256) void k_qkg(
    const float* __restrict__ x, const ushort* __restrict__ wkqb,
    const float* __restrict__ b_k, const float* __restrict__ b_q,
    ushort* __restrict__ kb, ushort* __restrict__ qb) {
  __shared__ __align__(16) ushort As[8][128][8];
  __shared__ __align__(16) ushort Bs[8][128][8];
  const int bm = blockIdx.x, by = blockIdx.y;
  const int gm0 = bm << 7;
  const int tid = threadIdx.x;
  const int lane = tid & 63, wid = tid >> 6;
  const int wm = wid >> 1, wn = wid & 1;
  const int srow = tid & 127;
  const int skg0 = tid >> 7;
  const ushort* wsrc = wkqb + by * 16384;
  f32x4 acc[4][4] = {};
  for (int kh = 0; kh < 2; ++kh) {
    __syncthreads();
#pragma unroll
    for (int j = 0; j < 4; ++j) {
      int kg = skg0 + 2 * j;
      const float* xp = x + (((size_t)(gm0 + srow)) << 7) + kh * 64 + kg * 8;
      float4 a0 = *(const float4*)xp;
      float4 a1 = *(const float4*)(xp + 4);
      uint4 pk;
      pk.x = (uint)f2bf(a0.x) | ((uint)f2bf(a0.y) << 16);
      pk.y = (uint)f2bf(a0.z) | ((uint)f2bf(a0.w) << 16);
      pk.z = (uint)f2bf(a1.x) | ((uint)f2bf(a1.y) << 16);
      pk.w = (uint)f2bf(a1.z) | ((uint)f2bf(a1.w) << 16);
      *(uint4*)&As[kg][srow][0] = pk;
      *(uint4*)&Bs[kg][srow][0] =
          *(const uint4*)&wsrc[(srow << 7) + kh * 64 + kg * 8];
    }
    __syncthreads();
#pragma unroll
    for (int ks = 0; ks < 2; ++ks) {
      int g = ks * 4 + (lane >> 4);
      bf16x8 af[4], bfr[4];
#pragma unroll
      for (int mi = 0; mi < 4; ++mi)
        af[mi] = *(const bf16x8*)&As[g][wm * 64 + mi * 16 + (lane & 15)][0];
#pragma unroll
      for (int ni = 0; ni < 4; ++ni)
        bfr[ni] = *(const bf16x8*)&Bs[g][wn * 64 + ni * 16 + (lane & 15)][0];
#pragma unroll
      for (int mi = 0; mi < 4; ++mi)
#pragma unroll
        for (int ni = 0; ni < 4; ++ni)
          acc[mi][ni] = __builtin_amdgcn_mfma_f32_16x16x32_bf16(
              af[mi], bfr[ni], acc[mi][ni], 0, 0, 0);
    }
  }
  const int l15 = lane & 15, l4 = lane >> 4;
  const float* bias = by ? b_q : b_k;
#pragma unroll
  for (int ni = 0; ni < 4; ++ni) {
    int col = wn * 64 + ni * 16 + l15;
    float bb = bias[col];
#pragma unroll
    for (int mi = 0; mi < 4; ++mi) {
#pragma unroll
      for (int reg = 0; reg < 4; ++reg) {
        int row = gm0 + wm * 64 + mi * 16 + (l4 << 2) + reg;
        ushort val = f2bf(acc[mi][ni][reg] + bb);
        if (by == 0) {
          kb[((size_t)row << 7) + col] = val;
        } else {
          int n = row / 7200;
          qb[((size_t)(row + n * 50 + 25) << 7) + col] = val;
        }
      }
    }
  }
}

// qb pad rows (tp=0, tp=289): bias-only.
__global__ __launch_bounds__(256) void k_qkpad(const float* __restrict__ b_q,
                                               ushort* __restrict__ qb) {
  int i = blockIdx.x * 256 + threadIdx.x;  // 16*2*25*128
  int o = i & 127;
  int r = i >> 7;
  int v = r % 25;
  int e = (r / 25) & 1;
  int n = r / 50;
  int tp = e ? 289 : 0;
  qb[((size_t)((n * TP + tp) * VV + v) << 7) + o] = f2bf(b_q[o]);
}

// ---------------- K2: scores (bf16 MFMA) + fused softmax -> attTb bf16 ----------------
// attTb[n][s][v(25)][u'(96)] with u' = w*32+vp, zero at vp>=25.
__global__ __launch_bounds__(512) void k_scores(
    const ushort* __restrict__ kb, const ushort* __restrict__ qb,
    const float* __restrict__ alphas, const float* __restrict__ att0,
    ushort* __restrict__ attTb) {
  __shared__ float red[8][2640];  // [wave][u(80) * 33 + v(32)]
  __shared__ float scl[1875];
  __shared__ float mx[25];
  __shared__ float den[25];
  const int bx = blockIdx.x;
  const int n = bx >> 3, s = bx & 7;
  const int tid = threadIdx.x;
  const int lane = tid & 63, wid = tid >> 6;
  const int l15 = lane & 15, l4 = lane >> 4;
  const int dt = l4 >> 1;
  const int sic = s * 16 + (l4 & 1) * 8;
  int qoff[5];
#pragma unroll
  for (int tu = 0; tu < 5; ++tu) {
    int u = tu * 16 + l15;
    int w = u / 25, vp = u - w * 25;
    qoff[tu] = (w * 25 + vp) * 128 + sic;
  }
  const bool qv4 = (64 + l15) < 75;
  const bool kv1 = (16 + l15) < 25;
  int koff0 = l15 * 128 + sic;
  int koff1 = (16 + l15) * 128 + sic;
  const ushort* qbase = qb + (size_t)n * 928000 + (size_t)dt * 3200;
  const ushort* kbase = kb + (size_t)n * 921600 + (size_t)dt * 3200;
  f32x4 acc[5][2] = {};
  const bf16x8 zf = {};
  for (int kk = wid; kk < 144; kk += 8) {
    const ushort* qp = qbase + kk * 6400;
    const ushort* kp = kbase + kk * 6400;
    bf16x8 a[5], b[2];
#pragma unroll
    for (int tu = 0; tu < 4; ++tu) a[tu] = *(const bf16x8*)(qp + qoff[tu]);
    a[4] = qv4 ? *(const bf16x8*)(qp + qoff[4]) : zf;
    b[0] = *(const bf16x8*)(kp + koff0);
    b[1] = kv1 ? *(const bf16x8*)(kp + koff1) : zf;
#pragma unroll
    for (int tu = 0; tu < 5; ++tu)
#pragma unroll
      for (int tv = 0; tv < 2; ++tv)
        acc[tu][tv] = __builtin_amdgcn_mfma_f32_16x16x32_bf16(
            a[tu], b[tv], acc[tu][tv], 0, 0, 0);
  }
#pragma unroll
  for (int tu = 0; tu < 5; ++tu)
#pragma unroll
    for (int tv = 0; tv < 2; ++tv) {
#pragma unroll
      for (int reg = 0; reg < 4; ++reg)
        red[wid][(tu * 16 + l4 * 4 + reg) * 33 + tv * 16 + l15] =
            acc[tu][tv][reg];
    }
  __syncthreads();
  const float inv = 1.0f / 4608.0f;
  for (int i = tid; i < 1875; i += 512) {
    int u = i / 25, v = i - u * 25;
    float a = 0.f;
#pragma unroll
    for (int w = 0; w < 8; ++w) a += red[w][u * 33 + v];
    scl[i] = a * inv;
  }
  __syncthreads();
  if (tid < 25) {
    float m = -1e30f;
    for (int u = 0; u < 75; ++u) m = fmaxf(m, scl[u * 25 + tid]);
    float d = 0.f;
    for (int u = 0; u < 75; ++u) d += expf(scl[u * 25 + tid] - m);
    mx[tid] = m;
    den[tid] = d;
  }
  __syncthreads();
  const float alpha = alphas[s];
  ushort* op = attTb + (size_t)bx * 2400;
  for (int i = tid; i < 2400; i += 512) {
    int v = i / 96, u = i - v * 96;
    int w = u >> 5, vp = u & 31;
    float val = 0.f;
    if (vp < 25) {
      int uo = w * 25 + vp;
      val = expf(scl[uo * 25 + v] - mx[v]) / den[v] * alpha +
            att0[(s * 75 + uo) * 25 + v];
    }
    op[i] = f2bf(val);
  }
}

// ---------------- K3: attention-apply + out conv (double MFMA, TB=2) ----------------
// Grid (144, 16): 2 t per block. 256 thr = 4 waves; wave wid owns c-range
// (step1) and o-range (step2) [wid*32, wid*32+32). A-frags direct from L2.
// Xt: 4 t-rows x 32 vp-slots shared by both t's; fragment base = tt*32.
__global__ __launch_bounds__(256, 3) void k_attn3(
    const float* __restrict__ x, const ushort* __restrict__ attTb,
    const ushort* __restrict__ wb, const float* __restrict__ b_out,
    const float* __restrict__ g_out, const float* __restrict__ beta_out,
    const float* __restrict__ m_out, const float* __restrict__ v_out,
    float* __restrict__ y1) {
  __shared__ __align__(16) uint4 Xt4[128 * 16];   // [c][chunk ^ (c&7)]
  __shared__ __align__(16) ushort Yl[2][32 * 136];
  const int t0 = blockIdx.x * 2, n = blockIdx.y;
  const int tid = threadIdx.x;
  // stage Xt: chunk = r*4 + vp0/8, r = t-row (tr = t0+r-1), u'-slot = r*32+vp
  for (int i = tid; i < 2048; i += 256) {
    int c = i & 127, chunk = i >> 7;
    int r = chunk >> 2, vp0 = (chunk & 3) * 8;
    int tr = t0 + r - 1;
    bool valid = (tr >= 0 && tr < TT);
    const float* xr = x + (((size_t)(n * TT + tr) * VV)) * 128 + c;
    float f[8];
#pragma unroll
    for (int j = 0; j < 8; ++j) {
      int vp = vp0 + j;
      f[j] = (valid && vp < 25) ? xr[vp * 128] : 0.f;
    }
    uint4 pk;
    pk.x = (uint)f2bf(f[0]) | ((uint)f2bf(f[1]) << 16);
    pk.y = (uint)f2bf(f[2]) | ((uint)f2bf(f[3]) << 16);
    pk.z = (uint)f2bf(f[4]) | ((uint)f2bf(f[5]) << 16);
    pk.w = (uint)f2bf(f[6]) | ((uint)f2bf(f[7]) << 16);
    Xt4[c * 16 + (chunk ^ (c & 7))] = pk;
  }
  __syncthreads();
  const int lane = tid & 63, wid = tid >> 6;
  const int l15 = lane & 15, l4 = lane >> 4;
  const bf16x8 zf = {};
  f32x4 accO[2][2][2] = {};  // [tt][mi(o)][nj(v)]
  const ushort* Avn = attTb + (size_t)n * 19200;
  const int c0r = wid * 32 + l15, c1r = wid * 32 + 16 + l15;
  for (int s = 0; s < 8; ++s) {
    const ushort* AvS = Avn + s * 2400;
    f32x4 accY[2][2][2] = {};  // [tt][mi(v)][nj(c)]
#pragma unroll
    for (int ks = 0; ks < 3; ++ks) {
      int u0 = ks * 32 + l4 * 8;
      bf16x8 av0 = *(const bf16x8*)&AvS[l15 * 96 + u0];
      int r1 = 16 + l15;
      bf16x8 av1 = *(const bf16x8*)&AvS[(r1 <= 24 ? r1 : 24) * 96 + u0];
      if (l15 > 8) av1 = zf;  // v >= 25 -> zero row
#pragma unroll
      for (int tt = 0; tt < 2; ++tt) {
        int ch = (tt + ks) * 4 + l4;
        bf16x8 xb0 = *(const bf16x8*)&Xt4[c0r * 16 + (ch ^ (c0r & 7))];
        bf16x8 xb1 = *(const bf16x8*)&Xt4[c1r * 16 + (ch ^ (c1r & 7))];
        accY[tt][0][0] = __builtin_amdgcn_mfma_f32_16x16x32_bf16(av0, xb0, accY[tt][0][0], 0, 0, 0);
        accY[tt][0][1] = __builtin_amdgcn_mfma_f32_16x16x32_bf16(av0, xb1, accY[tt][0][1], 0, 0, 0);
        accY[tt][1][0] = __builtin_amdgcn_mfma_f32_16x16x32_bf16(av1, xb0, accY[tt][1][0], 0, 0, 0);
        accY[tt][1][1] = __builtin_amdgcn_mfma_f32_16x16x32_bf16(av1, xb1, accY[tt][1][1], 0, 0, 0);
      }
    }
    __syncthreads();  // previous step-2 readers done with Yl
#pragma unroll
    for (int tt = 0; tt < 2; ++tt)
#pragma unroll
      for (int mi = 0; mi < 2; ++mi)
#pragma unroll
        for (int nj = 0; nj < 2; ++nj)
#pragma unroll
          for (int reg = 0; reg < 4; ++reg)
            Yl[tt][(mi * 16 + l4 * 4 + reg) * 136 + wid * 32 + nj * 16 + l15] =
                f2bf(accY[tt][mi][nj][reg]);
    __syncthreads();
    // ---- step 2: O[o, v] += W_s . Y_s ----
    const ushort* wS = wb + s * 16384;
#pragma unroll
    for (int kc = 0; kc < 4; ++kc) {
      int c0 = kc * 32 + l4 * 8;
      bf16x8 wf0 = *(const bf16x8*)&wS[(wid * 32 + l15) * 128 + c0];
      bf16x8 wf1 = *(const bf16x8*)&wS[(wid * 32 + 16 + l15) * 128 + c0];
#pragma unroll
      for (int tt = 0; tt < 2; ++tt) {
        bf16x8 yb0 = *(const bf16x8*)&Yl[tt][l15 * 136 + c0];
        bf16x8 yb1 = *(const bf16x8*)&Yl[tt][(16 + l15) * 136 + c0];
        accO[tt][0][0] = __builtin_amdgcn_mfma_f32_16x16x32_bf16(wf0, yb0, accO[tt][0][0], 0, 0, 0);
        accO[tt][0][1] = __builtin_amdgcn_mfma_f32_16x16x32_bf16(wf0, yb1, accO[tt][0][1], 0, 0, 0);
        accO[tt][1][0] = __builtin_amdgcn_mfma_f32_16x16x32_bf16(wf1, yb0, accO[tt][1][0], 0, 0, 0);
        accO[tt][1][1] = __builtin_amdgcn_mfma_f32_16x16x32_bf16(wf1, yb1, accO[tt][1][1], 0, 0, 0);
      }
    }
  }
  // ---- epilogue: BN + leaky(x + .) ----
#pragma unroll
  for (int tt = 0; tt < 2; ++tt) {
    int t = t0 + tt;
#pragma unroll
    for (int nj = 0; nj < 2; ++nj) {
      int v = nj * 16 + l15;
      if (v < 25) {
        size_t rowbase = (((size_t)(n * TT + t) * VV + v)) * 128 + wid * 32;
#pragma unroll
        for (int mi = 0; mi < 2; ++mi) {
          int ob = mi * 16 + (l4 << 2);
          int og = wid * 32 + ob;
          float4 gg = *(const float4*)&g_out[og];
          float4 vv = *(const float4*)&v_out[og];
          float4 mm = *(const float4*)&m_out[og];
          float4 be = *(const float4*)&beta_out[og];
          float4 bo = *(const float4*)&b_out[og];
          float4 xv = *(const float4*)&x[rowbase + ob];
          float4 r;
          float s1, a;
          s1 = gg.x * rsqrtf(vv.x + EPSF);
          a = (accO[tt][mi][nj][0] + bo.x) * s1 + (be.x - mm.x * s1) + xv.x;
          r.x = a > 0.f ? a : 0.1f * a;
          s1 = gg.y * rsqrtf(vv.y + EPSF);
          a = (accO[tt][mi][nj][1] + bo.y) * s1 + (be.y - mm.y * s1) + xv.y;
          r.y = a > 0.f ? a : 0.1f * a;
          s1 = gg.z * rsqrtf(vv.z + EPSF);
          a = (accO[tt][mi][nj][2] + bo.z) * s1 + (be.z - mm.z * s1) + xv.z;
          r.z = a > 0.f ? a : 0.1f * a;
          s1 = gg.w * rsqrtf(vv.w + EPSF);
          a = (accO[tt][mi][nj][3] + bo.w) * s1 + (be.w - mm.w * s1) + xv.w;
          r.w = a > 0.f ? a : 0.1f * a;
          *(float4*)&y1[rowbase + ob] = r;
        }
      }
    }
  }
}

// ---------------- K4: ff conv as bf16 MFMA GEMM + BN + leaky residual ----------------
__global__ __launch_bounds__(256) void k_ffg(
    const float* __restrict__ y1, const float* __restrict__ x,
    const ushort* __restrict__ wffb, const float* __restrict__ b_ff,
    const float* __restrict__ g_ff, const float* __restrict__ beta_ff,
    const float* __restrict__ m_ff, const float* __restrict__ v_ff,
    float* __restrict__ y2) {
  __shared__ __align__(16) ushort As[8][128][8];
  __shared__ __align__(16) ushort Bs[8][128][8];
  const int gm0 = blockIdx.x << 7;
  const int tid = threadIdx.x;
  const int lane = tid & 63, wid = tid >> 6;
  const int wm = wid >> 1, wn = wid & 1;
  const int srow = tid & 127;
  const int skg0 = tid >> 7;
  f32x4 acc[4][4] = {};
  for (int kh = 0; kh < 2; ++kh) {
    __syncthreads();
#pragma unroll
    for (int j = 0; j < 4; ++j) {
      int kg = skg0 + 2 * j;
      const float* yp = y1 + (((size_t)(gm0 + srow)) << 7) + kh * 64 + kg * 8;
      float4 a0 = *(const float4*)yp;
      float4 a1 = *(const float4*)(yp + 4);
      uint4 pk;
      pk.x = (uint)f2bf(a0.x) | ((uint)f2bf(a0.y) << 16);
      pk.y = (uint)f2bf(a0.z) | ((uint)f2bf(a0.w) << 16);
      pk.z = (uint)f2bf(a1.x) | ((uint)f2bf(a1.y) << 16);
      pk.w = (uint)f2bf(a1.z) | ((uint)f2bf(a1.w) << 16);
      *(uint4*)&As[kg][srow][0] = pk;
      *(uint4*)&Bs[kg][srow][0] =
          *(const uint4*)&wffb[(srow << 7) + kh * 64 + kg * 8];
    }
    __syncthreads();
#pragma unroll
    for (int ks = 0; ks < 2; ++ks) {
      int g = ks * 4 + (lane >> 4);
      bf16x8 af[4], bfr[4];
#pragma unroll
      for (int mi = 0; mi < 4; ++mi)
        af[mi] = *(const bf16x8*)&As[g][wm * 64 + mi * 16 + (lane & 15)][0];
#pragma unroll
      for (int ni = 0; ni < 4; ++ni)
        bfr[ni] = *(const bf16x8*)&Bs[g][wn * 64 + ni * 16 + (lane & 15)][0];
#pragma unroll
      for (int mi = 0; mi < 4; ++mi)
#pragma unroll
        for (int ni = 0; ni < 4; ++ni)
          acc[mi][ni] = __builtin_amdgcn_mfma_f32_16x16x32_bf16(
              af[mi], bfr[ni], acc[mi][ni], 0, 0, 0);
    }
  }
  const int l15 = lane & 15, l4 = lane >> 4;
#pragma unroll
  for (int ni = 0; ni < 4; ++ni) {
    int o = wn * 64 + ni * 16 + l15;
    float s1 = g_ff[o] * rsqrtf(v_ff[o] + EPSF);
    float sh = beta_ff[o] - m_ff[o] * s1;
    float bb = b_ff[o];
#pragma unroll
    for (int mi = 0; mi < 4; ++mi) {
#pragma unroll
      for (int reg = 0; reg < 4; ++reg) {
        int row = gm0 + wm * 64 + mi * 16 + (l4 << 2) + reg;
        size_t idx = ((size_t)row << 7) + o;
        float a = (acc[mi][ni][reg] + bb) * s1 + sh;
        float rr = x[idx] + a;
        y2[idx] = rr > 0.f ? rr : 0.1f * rr;
      }
    }
  }
}

// ---------------- K5a: w_t (o,c,kt) -> bf16 wbt[o][kt*128+c] ----------------
__global__ __launch_bounds__(256) void k_wtb(const float* __restrict__ w_t,
                                             ushort* __restrict__ wbt) {
  int i = blockIdx.x * 256 + threadIdx.x;
  if (i < 128 * 128 * 7) {
    int o = i / 896;
    int rem = i - o * 896;
    int c = rem / 7, kt = rem - c * 7;
    wbt[o * 896 + kt * 128 + c] = f2bf(w_t[i]);
  }
}

// ---------------- K5: temporal conv as bf16 MFMA GEMM ----------------
__global__ __launch_bounds__(256, 2) void k_tconv(
    const float* __restrict__ y2, const float* __restrict__ x,
    const ushort* __restrict__ wbt, const float* __restrict__ b_t,
    const float* __restrict__ g_t, const float* __restrict__ beta_t,
    const float* __restrict__ m_t, const float* __restrict__ v_t,
    float* __restrict__ out) {
  __shared__ __align__(16) uint4 As[280 * 16];  // [row][16B-chunk], ^(row&7)
  const int n = blockIdx.y;
  const int r0 = blockIdx.x << 7;
  const int tid = threadIdx.x;
  const float* y2n = y2 + ((size_t)n * 7200 << 7);
  for (int i = tid; i < 278 * 16; i += 256) {
    int rl = i >> 4, cc = i & 15;
    int g = r0 - 75 + rl;
    uint4 pk = make_uint4(0u, 0u, 0u, 0u);
    if (g >= 0 && g < 7200) {
      const float* xp = y2n + ((size_t)g << 7) + (cc << 3);
      float4 a0 = *(const float4*)xp;
      float4 a1 = *(const float4*)(xp + 4);
      pk.x = (uint)f2bf(a0.x) | ((uint)f2bf(a0.y) << 16);
      pk.y = (uint)f2bf(a0.z) | ((uint)f2bf(a0.w) << 16);
      pk.z = (uint)f2bf(a1.x) | ((uint)f2bf(a1.y) << 16);
      pk.w = (uint)f2bf(a1.z) | ((uint)f2bf(a1.w) << 16);
    }
    As[(rl << 4) + (cc ^ (rl & 7))] = pk;
  }
  __syncthreads();
  const int lane = tid & 63, wid = tid >> 6;
  const int wm = wid >> 1, wn = wid & 1;
  const int l15 = lane & 15, l4 = lane >> 4;
  f32x4 acc[4][4] = {};
  for (int kt = 0; kt < 7; ++kt) {
    bf16x8 bfr[4][4];
#pragma unroll
    for (int ni = 0; ni < 4; ++ni) {
      const ushort* bp =
          wbt + (size_t)(wn * 64 + ni * 16 + l15) * 896 + kt * 128 + l4 * 8;
#pragma unroll
      for (int cc0 = 0; cc0 < 4; ++cc0)
        bfr[ni][cc0] = *(const bf16x8*)(bp + cc0 * 32);
    }
#pragma unroll
    for (int cc0 = 0; cc0 < 4; ++cc0) {
      bf16x8 af[4];
#pragma unroll
      for (int mi = 0; mi < 4; ++mi) {
        int rl = wm * 64 + mi * 16 + l15 + 25 * kt;
        af[mi] = *(const bf16x8*)&As[(rl << 4) + ((cc0 * 4 + l4) ^ (rl & 7))];
      }
#pragma unroll
      for (int mi = 0; mi < 4; ++mi)
#pragma unroll
        for (int ni = 0; ni < 4; ++ni)
          acc[mi][ni] = __builtin_amdgcn_mfma_f32_16x16x32_bf16(
              af[mi], bfr[ni][cc0], acc[mi][ni], 0, 0, 0);
    }
  }
#pragma unroll
  for (int ni = 0; ni < 4; ++ni) {
    int o = wn * 64 + ni * 16 + l15;
    float s1 = g_t[o] * rsqrtf(v_t[o] + EPSF);
    float sh = beta_t[o] - m_t[o] * s1;
    float bb = b_t[o];
#pragma unroll
    for (int mi = 0; mi < 4; ++mi) {
#pragma unroll
      for (int reg = 0; reg < 4; ++reg) {
        int grow = r0 + wm * 64 + mi * 16 + (l4 << 2) + reg;
        if (grow < 7200) {
          size_t idx = (((size_t)n * 7200 + grow) << 7) + o;
          float z = (acc[mi][ni][reg] + bb) * s1 + sh;
          z += y2[idx];
          z = z > 0.f ? z : 0.1f * z;
          z += x[idx];
          out[idx] = z > 0.f ? z : 0.f;
        }
      }
    }
  }
}

extern "C" void kernel_launch(void* const* d_in, const int* in_sizes, int n_in,
                              void* d_out, int out_size, void* d_ws, size_t ws_size,
                              hipStream_t stream) {
  const float* x      = (const float*)d_in[0];
  const float* w_k    = (const float*)d_in[1];
  const float* b_k    = (const float*)d_in[2];
  const float* w_q    = (const float*)d_in[3];
  const float* b_q    = (const float*)d_in[4];
  const float* alphas = (const float*)d_in[5];
  const float* att0   = (const float*)d_in[6];
  const float* w_out  = (const float*)d_in[7];
  const float* b_out  = (const float*)d_in[8];
  const float* g_out  = (const float*)d_in[9];
  const float* be_out = (const float*)d_in[10];
  const float* m_out  = (const float*)d_in[11];
  const float* v_out  = (const float*)d_in[12];
  const float* w_ff   = (const float*)d_in[13];
  const float* b_ff   = (const float*)d_in[14];
  const float* g_ff   = (const float*)d_in[15];
  const float* be_ff  = (const float*)d_in[16];
  const float* m_ff   = (const float*)d_in[17];
  const float* v_ff   = (const float*)d_in[18];
  const float* w_t    = (const float*)d_in[19];
  const float* b_t    = (const float*)d_in[20];
  const float* g_t    = (const float*)d_in[21];
  const float* be_t   = (const float*)d_in[22];
  const float* m_t    = (const float*)d_in[23];
  const float* v_t    = (const float*)d_in[24];

  float* ws = (float*)d_ws;
  // Region plan (floats), total 32,108,288 = round-1 proven footprint:
  float* qfull = ws;               // [0, 14848000)   qb bf16 -> y2
  float* kfull = ws + 14848000;    // [.., +14745600) kb bf16 -> y1
  float* part  = ws + 29593600;    // [.., +2160000)  wb/wkqb/wffb bf16
  float* attr  = ws + 31753600;    // [.., +240000)   attTb bf16 (307200 sh)
  float* wtr   = ws + 31993600;    // [.., +114688)   wbt bf16
  ushort* qbb   = (ushort*)qfull;
  ushort* kbb   = (ushort*)kfull;
  ushort* wb    = (ushort*)part;            // 131072 shorts
  ushort* wkqb  = (ushort*)part + 131072;   //  32768 shorts
  ushort* wffb  = (ushort*)part + 163840;   //  16384 shorts
  ushort* attTb = (ushort*)attr;
  ushort* wbt   = (ushort*)wtr;
  float* y1 = kfull;
  float* y2 = qfull;
  float* outp = (float*)d_out;

  k_wcvt<<<704, 256, 0, stream>>>(w_out, w_k, w_q, w_ff, wb, wkqb, wffb);
  k_qkg<<<dim3(900, 2), 256, 0, stream>>>(x, wkqb, b_k, b_q, kbb, qbb);
  k_qkpad<<<400, 256, 0, stream>>>(b_q, qbb);
  k_scores<<<128, 512, 0, stream>>>(kbb, qbb, alphas, att0, attTb);
  k_attn3<<<dim3(144, 16), 256, 0, stream>>>(x, attTb, wb, b_out, g_out,
                                             be_out, m_out, v_out, y1);
  k_ffg<<<900, 256, 0, stream>>>(y1, x, wffb, b_ff, g_ff, be_ff, m_ff, v_ff, y2);
  k_wtb<<<448, 256, 0, stream>>>(w_t, wbt);
  k_tconv<<<dim3(57, 16), 256, 0, stream>>>(y2, x, wbt, b_t, g_t, be_t, m_t,
                                            v_t, outp);
}

// Round 13
// 376.637 us; speedup vs baseline: 3.0496x; 1.0633x over previous
//
#include <hip/hip_runtime.h>

// SSHA block. Round 13: (a) k_ffg fused into k_attn3 — after the s-loop each
// block holds complete y1 rows for its 2 t's; y1 goes to LDS (bf16, reusing
// Yl), ff GEMM (K=128) + BN + leaky residual run in-block; y1 never hits HBM.
// (b) Xt4 layout transposed to [chunk][c] (no XOR) — staging writes and
// fragment reads both lane-contiguous => conflict-free.
// Everything else identical to round 12.
// Shapes: N=16, T=288, V=25, C=128, S=8, IC=16, W=3, U=75, TP=290.

#define NN 16
#define TT 288
#define VV 25
#define CC 128
#define SS 8
#define UU 75
#define TP 290
#define EPSF 1e-5f

typedef __attribute__((ext_vector_type(8))) short bf16x8;
typedef __attribute__((ext_vector_type(4))) float f32x4;

static __device__ __forceinline__ ushort f2bf(float f) {
  uint u = __float_as_uint(f);
  u = (u + 0x7FFFu + ((u >> 16) & 1u)) >> 16;
  return (ushort)u;
}

// ---------------- K0: weight converts ----------------
__global__ __launch_bounds__(256) void k_wcvt(
    const float* __restrict__ w_out, const float* __restrict__ w_k,
    const float* __restrict__ w_q, const float* __restrict__ w_ff,
    ushort* __restrict__ wb, ushort* __restrict__ wkqb,
    ushort* __restrict__ wffb) {
  int i = blockIdx.x * 256 + threadIdx.x;  // 180224 total
  if (i < 131072) {
    int j = i >> 7, c = i & 127;
    int s = j >> 7, o = j & 127;
    wb[i] = f2bf(w_out[(o << 10) + (s << 7) + c]);
  } else {
    int j = i - 131072;
    if (j < 16384) wkqb[j] = f2bf(w_k[j]);
    else if (j < 32768) wkqb[j] = f2bf(w_q[j - 16384]);
    else wffb[j - 32768] = f2bf(w_ff[j - 32768]);
  }
}

// ---------------- K1: k/q 1x1 convs as bf16 MFMA GEMM ----------------
__global__ __launch_bounds__(256) void k_qkg(
    const float* __restrict__ x, const ushort* __restrict__ wkqb,
    const float* __restrict__ b_k, const float* __restrict__ b_q,
    ushort* __restrict__ kb, ushort* __restrict__ qb) {
  __shared__ __align__(16) ushort As[8][128][8];
  __shared__ __align__(16) ushort Bs[8][128][8];
  const int bm = blockIdx.x, by = blockIdx.y;
  const int gm0 = bm << 7;
  const int tid = threadIdx.x;
  const int lane = tid & 63, wid = tid >> 6;
  const int wm = wid >> 1, wn = wid & 1;
  const int srow = tid & 127;
  const int skg0 = tid >> 7;
  const ushort* wsrc = wkqb + by * 16384;
  f32x4 acc[4][4] = {};
  for (int kh = 0; kh < 2; ++kh) {
    __syncthreads();
#pragma unroll
    for (int j = 0; j < 4; ++j) {
      int kg = skg0 + 2 * j;
      const float* xp = x + (((size_t)(gm0 + srow)) << 7) + kh * 64 + kg * 8;
      float4 a0 = *(const float4*)xp;
      float4 a1 = *(const float4*)(xp + 4);
      uint4 pk;
      pk.x = (uint)f2bf(a0.x) | ((uint)f2bf(a0.y) << 16);
      pk.y = (uint)f2bf(a0.z) | ((uint)f2bf(a0.w) << 16);
      pk.z = (uint)f2bf(a1.x) | ((uint)f2bf(a1.y) << 16);
      pk.w = (uint)f2bf(a1.z) | ((uint)f2bf(a1.w) << 16);
      *(uint4*)&As[kg][srow][0] = pk;
      *(uint4*)&Bs[kg][srow][0] =
          *(const uint4*)&wsrc[(srow << 7) + kh * 64 + kg * 8];
    }
    __syncthreads();
#pragma unroll
    for (int ks = 0; ks < 2; ++ks) {
      int g = ks * 4 + (lane >> 4);
      bf16x8 af[4], bfr[4];
#pragma unroll
      for (int mi = 0; mi < 4; ++mi)
        af[mi] = *(const bf16x8*)&As[g][wm * 64 + mi * 16 + (lane & 15)][0];
#pragma unroll
      for (int ni = 0; ni < 4; ++ni)
        bfr[ni] = *(const bf16x8*)&Bs[g][wn * 64 + ni * 16 + (lane & 15)][0];
#pragma unroll
      for (int mi = 0; mi < 4; ++mi)
#pragma unroll
        for (int ni = 0; ni < 4; ++ni)
          acc[mi][ni] = __builtin_amdgcn_mfma_f32_16x16x32_bf16(
              af[mi], bfr[ni], acc[mi][ni], 0, 0, 0);
    }
  }
  const int l15 = lane & 15, l4 = lane >> 4;
  const float* bias = by ? b_q : b_k;
#pragma unroll
  for (int ni = 0; ni < 4; ++ni) {
    int col = wn * 64 + ni * 16 + l15;
    float bb = bias[col];
#pragma unroll
    for (int mi = 0; mi < 4; ++mi) {
#pragma unroll
      for (int reg = 0; reg < 4; ++reg) {
        int row = gm0 + wm * 64 + mi * 16 + (l4 << 2) + reg;
        ushort val = f2bf(acc[mi][ni][reg] + bb);
        if (by == 0) {
          kb[((size_t)row << 7) + col] = val;
        } else {
          int n = row / 7200;
          qb[((size_t)(row + n * 50 + 25) << 7) + col] = val;
        }
      }
    }
  }
}

// qb pad rows (tp=0, tp=289): bias-only.
__global__ __launch_bounds__(256) void k_qkpad(const float* __restrict__ b_q,
                                               ushort* __restrict__ qb) {
  int i = blockIdx.x * 256 + threadIdx.x;  // 16*2*25*128
  int o = i & 127;
  int r = i >> 7;
  int v = r % 25;
  int e = (r / 25) & 1;
  int n = r / 50;
  int tp = e ? 289 : 0;
  qb[((size_t)((n * TP + tp) * VV + v) << 7) + o] = f2bf(b_q[o]);
}

// ---------------- K2: scores (bf16 MFMA) + fused softmax -> attTb bf16 ----------------
// attTb[n][s][v(25)][u'(96)] with u' = w*32+vp, zero at vp>=25.
__global__ __launch_bounds__(512) void k_scores(
    const ushort* __restrict__ kb, const ushort* __restrict__ qb,
    const float* __restrict__ alphas, const float* __restrict__ att0,
    ushort* __restrict__ attTb) {
  __shared__ float red[8][2640];  // [wave][u(80) * 33 + v(32)]
  __shared__ float scl[1875];
  __shared__ float mx[25];
  __shared__ float den[25];
  const int bx = blockIdx.x;
  const int n = bx >> 3, s = bx & 7;
  const int tid = threadIdx.x;
  const int lane = tid & 63, wid = tid >> 6;
  const int l15 = lane & 15, l4 = lane >> 4;
  const int dt = l4 >> 1;
  const int sic = s * 16 + (l4 & 1) * 8;
  int qoff[5];
#pragma unroll
  for (int tu = 0; tu < 5; ++tu) {
    int u = tu * 16 + l15;
    int w = u / 25, vp = u - w * 25;
    qoff[tu] = (w * 25 + vp) * 128 + sic;
  }
  const bool qv4 = (64 + l15) < 75;
  const bool kv1 = (16 + l15) < 25;
  int koff0 = l15 * 128 + sic;
  int koff1 = (16 + l15) * 128 + sic;
  const ushort* qbase = qb + (size_t)n * 928000 + (size_t)dt * 3200;
  const ushort* kbase = kb + (size_t)n * 921600 + (size_t)dt * 3200;
  f32x4 acc[5][2] = {};
  const bf16x8 zf = {};
  for (int kk = wid; kk < 144; kk += 8) {
    const ushort* qp = qbase + kk * 6400;
    const ushort* kp = kbase + kk * 6400;
    bf16x8 a[5], b[2];
#pragma unroll
    for (int tu = 0; tu < 4; ++tu) a[tu] = *(const bf16x8*)(qp + qoff[tu]);
    a[4] = qv4 ? *(const bf16x8*)(qp + qoff[4]) : zf;
    b[0] = *(const bf16x8*)(kp + koff0);
    b[1] = kv1 ? *(const bf16x8*)(kp + koff1) : zf;
#pragma unroll
    for (int tu = 0; tu < 5; ++tu)
#pragma unroll
      for (int tv = 0; tv < 2; ++tv)
        acc[tu][tv] = __builtin_amdgcn_mfma_f32_16x16x32_bf16(
            a[tu], b[tv], acc[tu][tv], 0, 0, 0);
  }
#pragma unroll
  for (int tu = 0; tu < 5; ++tu)
#pragma unroll
    for (int tv = 0; tv < 2; ++tv) {
#pragma unroll
      for (int reg = 0; reg < 4; ++reg)
        red[wid][(tu * 16 + l4 * 4 + reg) * 33 + tv * 16 + l15] =
            acc[tu][tv][reg];
    }
  __syncthreads();
  const float inv = 1.0f / 4608.0f;
  for (int i = tid; i < 1875; i += 512) {
    int u = i / 25, v = i - u * 25;
    float a = 0.f;
#pragma unroll
    for (int w = 0; w < 8; ++w) a += red[w][u * 33 + v];
    scl[i] = a * inv;
  }
  __syncthreads();
  if (tid < 25) {
    float m = -1e30f;
    for (int u = 0; u < 75; ++u) m = fmaxf(m, scl[u * 25 + tid]);
    float d = 0.f;
    for (int u = 0; u < 75; ++u) d += expf(scl[u * 25 + tid] - m);
    mx[tid] = m;
    den[tid] = d;
  }
  __syncthreads();
  const float alpha = alphas[s];
  ushort* op = attTb + (size_t)bx * 2400;
  for (int i = tid; i < 2400; i += 512) {
    int v = i / 96, u = i - v * 96;
    int w = u >> 5, vp = u & 31;
    float val = 0.f;
    if (vp < 25) {
      int uo = w * 25 + vp;
      val = expf(scl[uo * 25 + v] - mx[v]) / den[v] * alpha +
            att0[(s * 75 + uo) * 25 + v];
    }
    op[i] = f2bf(val);
  }
}

// ---------------- K3: attention-apply + out conv + FF conv (triple MFMA, TB=2) ----------------
// Grid (144, 16): 2 t per block. 256 thr = 4 waves; wave wid owns c-range
// (steps 1/2) and o-range (steps 2/3) [wid*32, wid*32+32).
// Xt4 layout [chunk][c]: staging writes and fragment reads lane-contiguous.
// After the s-loop, y1 (post BN+leaky) goes to Yl as bf16 and the ff GEMM +
// BN + leaky residual run in-block -> y2. y1 never touches HBM.
__global__ __launch_bounds__(256, 3) void k_attn3(
    const float* __restrict__ x, const ushort* __restrict__ attTb,
    const ushort* __restrict__ wb, const float* __restrict__ b_out,
    const float* __restrict__ g_out, const float* __restrict__ beta_out,
    const float* __restrict__ m_out, const float* __restrict__ v_out,
    const ushort* __restrict__ wffb, const float* __restrict__ b_ff,
    const float* __restrict__ g_ff, const float* __restrict__ beta_ff,
    const float* __restrict__ m_ff, const float* __restrict__ v_ff,
    float* __restrict__ y2) {
  __shared__ __align__(16) uint4 Xt4[16 * 128];  // [chunk][c]
  __shared__ __align__(16) ushort Yl[2][32 * 136];
  const int t0 = blockIdx.x * 2, n = blockIdx.y;
  const int tid = threadIdx.x;
  // stage Xt: chunk = r*4 + vp0/8 (r = t-row, tr = t0+r-1), c lane-fast.
  for (int i = tid; i < 2048; i += 256) {
    int c = i & 127, chunk = i >> 7;
    int r = chunk >> 2, vp0 = (chunk & 3) * 8;
    int tr = t0 + r - 1;
    bool valid = (tr >= 0 && tr < TT);
    const float* xr = x + (((size_t)(n * TT + tr) * VV)) * 128 + c;
    float f[8];
#pragma unroll
    for (int j = 0; j < 8; ++j) {
      int vp = vp0 + j;
      f[j] = (valid && vp < 25) ? xr[vp * 128] : 0.f;
    }
    uint4 pk;
    pk.x = (uint)f2bf(f[0]) | ((uint)f2bf(f[1]) << 16);
    pk.y = (uint)f2bf(f[2]) | ((uint)f2bf(f[3]) << 16);
    pk.z = (uint)f2bf(f[4]) | ((uint)f2bf(f[5]) << 16);
    pk.w = (uint)f2bf(f[6]) | ((uint)f2bf(f[7]) << 16);
    Xt4[chunk * 128 + c] = pk;
  }
  __syncthreads();
  const int lane = tid & 63, wid = tid >> 6;
  const int l15 = lane & 15, l4 = lane >> 4;
  const bf16x8 zf = {};
  f32x4 accO[2][2][2] = {};  // [tt][mi(o)][nj(v)]
  const ushort* Avn = attTb + (size_t)n * 19200;
  const int c0r = wid * 32 + l15, c1r = wid * 32 + 16 + l15;
  for (int s = 0; s < 8; ++s) {
    const ushort* AvS = Avn + s * 2400;
    f32x4 accY[2][2][2] = {};  // [tt][mi(v)][nj(c)]
#pragma unroll
    for (int ks = 0; ks < 3; ++ks) {
      int u0 = ks * 32 + l4 * 8;
      bf16x8 av0 = *(const bf16x8*)&AvS[l15 * 96 + u0];
      int r1 = 16 + l15;
      bf16x8 av1 = *(const bf16x8*)&AvS[(r1 <= 24 ? r1 : 24) * 96 + u0];
      if (l15 > 8) av1 = zf;  // v >= 25 -> zero row
#pragma unroll
      for (int tt = 0; tt < 2; ++tt) {
        int ch = (tt + ks) * 4 + l4;
        bf16x8 xb0 = *(const bf16x8*)&Xt4[ch * 128 + c0r];
        bf16x8 xb1 = *(const bf16x8*)&Xt4[ch * 128 + c1r];
        accY[tt][0][0] = __builtin_amdgcn_mfma_f32_16x16x32_bf16(av0, xb0, accY[tt][0][0], 0, 0, 0);
        accY[tt][0][1] = __builtin_amdgcn_mfma_f32_16x16x32_bf16(av0, xb1, accY[tt][0][1], 0, 0, 0);
        accY[tt][1][0] = __builtin_amdgcn_mfma_f32_16x16x32_bf16(av1, xb0, accY[tt][1][0], 0, 0, 0);
        accY[tt][1][1] = __builtin_amdgcn_mfma_f32_16x16x32_bf16(av1, xb1, accY[tt][1][1], 0, 0, 0);
      }
    }
    __syncthreads();  // previous step-2 readers done with Yl
#pragma unroll
    for (int tt = 0; tt < 2; ++tt)
#pragma unroll
      for (int mi = 0; mi < 2; ++mi)
#pragma unroll
        for (int nj = 0; nj < 2; ++nj)
#pragma unroll
          for (int reg = 0; reg < 4; ++reg)
            Yl[tt][(mi * 16 + l4 * 4 + reg) * 136 + wid * 32 + nj * 16 + l15] =
                f2bf(accY[tt][mi][nj][reg]);
    __syncthreads();
    // ---- step 2: O[o, v] += W_s . Y_s ----
    const ushort* wS = wb + s * 16384;
#pragma unroll
    for (int kc = 0; kc < 4; ++kc) {
      int c0 = kc * 32 + l4 * 8;
      bf16x8 wf0 = *(const bf16x8*)&wS[(wid * 32 + l15) * 128 + c0];
      bf16x8 wf1 = *(const bf16x8*)&wS[(wid * 32 + 16 + l15) * 128 + c0];
#pragma unroll
      for (int tt = 0; tt < 2; ++tt) {
        bf16x8 yb0 = *(const bf16x8*)&Yl[tt][l15 * 136 + c0];
        bf16x8 yb1 = *(const bf16x8*)&Yl[tt][(16 + l15) * 136 + c0];
        accO[tt][0][0] = __builtin_amdgcn_mfma_f32_16x16x32_bf16(wf0, yb0, accO[tt][0][0], 0, 0, 0);
        accO[tt][0][1] = __builtin_amdgcn_mfma_f32_16x16x32_bf16(wf0, yb1, accO[tt][0][1], 0, 0, 0);
        accO[tt][1][0] = __builtin_amdgcn_mfma_f32_16x16x32_bf16(wf1, yb0, accO[tt][1][0], 0, 0, 0);
        accO[tt][1][1] = __builtin_amdgcn_mfma_f32_16x16x32_bf16(wf1, yb1, accO[tt][1][1], 0, 0, 0);
      }
    }
  }
  // ---- y1 epilogue: BN + leaky(x + .), write bf16 to Yl (v>=25 rows = 0) ----
  __syncthreads();  // last step-2 Yl reads complete
#pragma unroll
  for (int tt = 0; tt < 2; ++tt) {
    int t = t0 + tt;
#pragma unroll
    for (int nj = 0; nj < 2; ++nj) {
      int v = nj * 16 + l15;
      ushort pv[2][4];
      if (v < 25) {
        size_t rowbase = (((size_t)(n * TT + t) * VV + v)) * 128 + wid * 32;
#pragma unroll
        for (int mi = 0; mi < 2; ++mi) {
          int ob = mi * 16 + (l4 << 2);
          int og = wid * 32 + ob;
          float4 gg = *(const float4*)&g_out[og];
          float4 vv = *(const float4*)&v_out[og];
          float4 mm = *(const float4*)&m_out[og];
          float4 be = *(const float4*)&beta_out[og];
          float4 bo = *(const float4*)&b_out[og];
          float4 xv = *(const float4*)&x[rowbase + ob];
          float s1, a;
          s1 = gg.x * rsqrtf(vv.x + EPSF);
          a = (accO[tt][mi][nj][0] + bo.x) * s1 + (be.x - mm.x * s1) + xv.x;
          pv[mi][0] = f2bf(a > 0.f ? a : 0.1f * a);
          s1 = gg.y * rsqrtf(vv.y + EPSF);
          a = (accO[tt][mi][nj][1] + bo.y) * s1 + (be.y - mm.y * s1) + xv.y;
          pv[mi][1] = f2bf(a > 0.f ? a : 0.1f * a);
          s1 = gg.z * rsqrtf(vv.z + EPSF);
          a = (accO[tt][mi][nj][2] + bo.z) * s1 + (be.z - mm.z * s1) + xv.z;
          pv[mi][2] = f2bf(a > 0.f ? a : 0.1f * a);
          s1 = gg.w * rsqrtf(vv.w + EPSF);
          a = (accO[tt][mi][nj][3] + bo.w) * s1 + (be.w - mm.w * s1) + xv.w;
          pv[mi][3] = f2bf(a > 0.f ? a : 0.1f * a);
        }
      } else {
#pragma unroll
        for (int mi = 0; mi < 2; ++mi)
#pragma unroll
          for (int reg = 0; reg < 4; ++reg) pv[mi][reg] = 0;
      }
#pragma unroll
      for (int mi = 0; mi < 2; ++mi)
#pragma unroll
        for (int reg = 0; reg < 4; ++reg)
          Yl[tt][v * 136 + wid * 32 + mi * 16 + (l4 << 2) + reg] = pv[mi][reg];
    }
  }
  __syncthreads();
  // ---- step 3: FF = W_ff . y1 (K=128) ----
  f32x4 accF[2][2][2] = {};  // [tt][mi(o)][nj(v)]
#pragma unroll
  for (int kc = 0; kc < 4; ++kc) {
    int c0 = kc * 32 + l4 * 8;
    bf16x8 wf0 = *(const bf16x8*)&wffb[(wid * 32 + l15) * 128 + c0];
    bf16x8 wf1 = *(const bf16x8*)&wffb[(wid * 32 + 16 + l15) * 128 + c0];
#pragma unroll
    for (int tt = 0; tt < 2; ++tt) {
      bf16x8 yb0 = *(const bf16x8*)&Yl[tt][l15 * 136 + c0];
      bf16x8 yb1 = *(const bf16x8*)&Yl[tt][(16 + l15) * 136 + c0];
      accF[tt][0][0] = __builtin_amdgcn_mfma_f32_16x16x32_bf16(wf0, yb0, accF[tt][0][0], 0, 0, 0);
      accF[tt][0][1] = __builtin_amdgcn_mfma_f32_16x16x32_bf16(wf0, yb1, accF[tt][0][1], 0, 0, 0);
      accF[tt][1][0] = __builtin_amdgcn_mfma_f32_16x16x32_bf16(wf1, yb0, accF[tt][1][0], 0, 0, 0);
      accF[tt][1][1] = __builtin_amdgcn_mfma_f32_16x16x32_bf16(wf1, yb1, accF[tt][1][1], 0, 0, 0);
    }
  }
  // ---- ff epilogue: y2 = leaky(x + BN_ff(FF + b_ff)) ----
#pragma unroll
  for (int tt = 0; tt < 2; ++tt) {
    int t = t0 + tt;
#pragma unroll
    for (int nj = 0; nj < 2; ++nj) {
      int v = nj * 16 + l15;
      if (v < 25) {
        size_t rowbase = (((size_t)(n * TT + t) * VV + v)) * 128 + wid * 32;
#pragma unroll
        for (int mi = 0; mi < 2; ++mi) {
          int ob = mi * 16 + (l4 << 2);
          int og = wid * 32 + ob;
          float4 gg = *(const float4*)&g_ff[og];
          float4 vv = *(const float4*)&v_ff[og];
          float4 mm = *(const float4*)&m_ff[og];
          float4 be = *(const float4*)&beta_ff[og];
          float4 bo = *(const float4*)&b_ff[og];
          float4 xv = *(const float4*)&x[rowbase + ob];
          float4 r;
          float s1, a;
          s1 = gg.x * rsqrtf(vv.x + EPSF);
          a = (accF[tt][mi][nj][0] + bo.x) * s1 + (be.x - mm.x * s1) + xv.x;
          r.x = a > 0.f ? a : 0.1f * a;
          s1 = gg.y * rsqrtf(vv.y + EPSF);
          a = (accF[tt][mi][nj][1] + bo.y) * s1 + (be.y - mm.y * s1) + xv.y;
          r.y = a > 0.f ? a : 0.1f * a;
          s1 = gg.z * rsqrtf(vv.z + EPSF);
          a = (accF[tt][mi][nj][2] + bo.z) * s1 + (be.z - mm.z * s1) + xv.z;
          r.z = a > 0.f ? a : 0.1f * a;
          s1 = gg.w * rsqrtf(vv.w + EPSF);
          a = (accF[tt][mi][nj][3] + bo.w) * s1 + (be.w - mm.w * s1) + xv.w;
          r.w = a > 0.f ? a : 0.1f * a;
          *(float4*)&y2[rowbase + ob] = r;
        }
      }
    }
  }
}

// ---------------- K5a: w_t (o,c,kt) -> bf16 wbt[o][kt*128+c] ----------------
__global__ __launch_bounds__(256) void k_wtb(const float* __restrict__ w_t,
                                             ushort* __restrict__ wbt) {
  int i = blockIdx.x * 256 + threadIdx.x;
  if (i < 128 * 128 * 7) {
    int o = i / 896;
    int rem = i - o * 896;
    int c = rem / 7, kt = rem - c * 7;
    wbt[o * 896 + kt * 128 + c] = f2bf(w_t[i]);
  }
}

// ---------------- K5: temporal conv as bf16 MFMA GEMM ----------------
__global__ __launch_bounds__(256, 2) void k_tconv(
    const float* __restrict__ y2, const float* __restrict__ x,
    const ushort* __restrict__ wbt, const float* __restrict__ b_t,
    const float* __restrict__ g_t, const float* __restrict__ beta_t,
    const float* __restrict__ m_t, const float* __restrict__ v_t,
    float* __restrict__ out) {
  __shared__ __align__(16) uint4 As[280 * 16];  // [row][16B-chunk], ^(row&7)
  const int n = blockIdx.y;
  const int r0 = blockIdx.x << 7;
  const int tid = threadIdx.x;
  const float* y2n = y2 + ((size_t)n * 7200 << 7);
  for (int i = tid; i < 278 * 16; i += 256) {
    int rl = i >> 4, cc = i & 15;
    int g = r0 - 75 + rl;
    uint4 pk = make_uint4(0u, 0u, 0u, 0u);
    if (g >= 0 && g < 7200) {
      const float* xp = y2n + ((size_t)g << 7) + (cc << 3);
      float4 a0 = *(const float4*)xp;
      float4 a1 = *(const float4*)(xp + 4);
      pk.x = (uint)f2bf(a0.x) | ((uint)f2bf(a0.y) << 16);
      pk.y = (uint)f2bf(a0.z) | ((uint)f2bf(a0.w) << 16);
      pk.z = (uint)f2bf(a1.x) | ((uint)f2bf(a1.y) << 16);
      pk.w = (uint)f2bf(a1.z) | ((uint)f2bf(a1.w) << 16);
    }
    As[(rl << 4) + (cc ^ (rl & 7))] = pk;
  }
  __syncthreads();
  const int lane = tid & 63, wid = tid >> 6;
  const int wm = wid >> 1, wn = wid & 1;
  const int l15 = lane & 15, l4 = lane >> 4;
  f32x4 acc[4][4] = {};
  for (int kt = 0; kt < 7; ++kt) {
    bf16x8 bfr[4][4];
#pragma unroll
    for (int ni = 0; ni < 4; ++ni) {
      const ushort* bp =
          wbt + (size_t)(wn * 64 + ni * 16 + l15) * 896 + kt * 128 + l4 * 8;
#pragma unroll
      for (int cc0 = 0; cc0 < 4; ++cc0)
        bfr[ni][cc0] = *(const bf16x8*)(bp + cc0 * 32);
    }
#pragma unroll
    for (int cc0 = 0; cc0 < 4; ++cc0) {
      bf16x8 af[4];
#pragma unroll
      for (int mi = 0; mi < 4; ++mi) {
        int rl = wm * 64 + mi * 16 + l15 + 25 * kt;
        af[mi] = *(const bf16x8*)&As[(rl << 4) + ((cc0 * 4 + l4) ^ (rl & 7))];
      }
#pragma unroll
      for (int mi = 0; mi < 4; ++mi)
#pragma unroll
        for (int ni = 0; ni < 4; ++ni)
          acc[mi][ni] = __builtin_amdgcn_mfma_f32_16x16x32_bf16(
              af[mi], bfr[ni][cc0], acc[mi][ni], 0, 0, 0);
    }
  }
#pragma unroll
  for (int ni = 0; ni < 4; ++ni) {
    int o = wn * 64 + ni * 16 + l15;
    float s1 = g_t[o] * rsqrtf(v_t[o] + EPSF);
    float sh = beta_t[o] - m_t[o] * s1;
    float bb = b_t[o];
#pragma unroll
    for (int mi = 0; mi < 4; ++mi) {
#pragma unroll
      for (int reg = 0; reg < 4; ++reg) {
        int grow = r0 + wm * 64 + mi * 16 + (l4 << 2) + reg;
        if (grow < 7200) {
          size_t idx = (((size_t)n * 7200 + grow) << 7) + o;
          float z = (acc[mi][ni][reg] + bb) * s1 + sh;
          z += y2[idx];
          z = z > 0.f ? z : 0.1f * z;
          z += x[idx];
          out[idx] = z > 0.f ? z : 0.f;
        }
      }
    }
  }
}

extern "C" void kernel_launch(void* const* d_in, const int* in_sizes, int n_in,
                              void* d_out, int out_size, void* d_ws, size_t ws_size,
                              hipStream_t stream) {
  const float* x      = (const float*)d_in[0];
  const float* w_k    = (const float*)d_in[1];
  const float* b_k    = (const float*)d_in[2];
  const float* w_q    = (const float*)d_in[3];
  const float* b_q    = (const float*)d_in[4];
  const float* alphas = (const float*)d_in[5];
  const float* att0   = (const float*)d_in[6];
  const float* w_out  = (const float*)d_in[7];
  const float* b_out  = (const float*)d_in[8];
  const float* g_out  = (const float*)d_in[9];
  const float* be_out = (const float*)d_in[10];
  const float* m_out  = (const float*)d_in[11];
  const float* v_out  = (const float*)d_in[12];
  const float* w_ff   = (const float*)d_in[13];
  const float* b_ff   = (const float*)d_in[14];
  const float* g_ff   = (const float*)d_in[15];
  const float* be_ff  = (const float*)d_in[16];
  const float* m_ff   = (const float*)d_in[17];
  const float* v_ff   = (const float*)d_in[18];
  const float* w_t    = (const float*)d_in[19];
  const float* b_t    = (const float*)d_in[20];
  const float* g_t    = (const float*)d_in[21];
  const float* be_t   = (const float*)d_in[22];
  const float* m_t    = (const float*)d_in[23];
  const float* v_t    = (const float*)d_in[24];

  float* ws = (float*)d_ws;
  // Region plan (floats), total 32,108,288 = round-1 proven footprint:
  float* qfull = ws;               // [0, 14848000)   qb bf16 -> y2
  float* kfull = ws + 14848000;    // [.., +14745600) kb bf16
  float* part  = ws + 29593600;    // [.., +2160000)  wb/wkqb/wffb bf16
  float* attr  = ws + 31753600;    // [.., +240000)   attTb bf16 (307200 sh)
  float* wtr   = ws + 31993600;    // [.., +114688)   wbt bf16
  ushort* qbb   = (ushort*)qfull;
  ushort* kbb   = (ushort*)kfull;
  ushort* wb    = (ushort*)part;            // 131072 shorts
  ushort* wkqb  = (ushort*)part + 131072;   //  32768 shorts
  ushort* wffb  = (ushort*)part + 163840;   //  16384 shorts
  ushort* attTb = (ushort*)attr;
  ushort* wbt   = (ushort*)wtr;
  float* y2 = qfull;
  float* outp = (float*)d_out;

  k_wcvt<<<704, 256, 0, stream>>>(w_out, w_k, w_q, w_ff, wb, wkqb, wffb);
  k_qkg<<<dim3(900, 2), 256, 0, stream>>>(x, wkqb, b_k, b_q, kbb, qbb);
  k_qkpad<<<400, 256, 0, stream>>>(b_q, qbb);
  k_scores<<<128, 512, 0, stream>>>(kbb, qbb, alphas, att0, attTb);
  k_attn3<<<dim3(144, 16), 256, 0, stream>>>(x, attTb, wb, b_out, g_out,
                                             be_out, m_out, v_out, wffb, b_ff,
                                             g_ff, be_ff, m_ff, v_ff, y2);
  k_wtb<<<448, 256, 0, stream>>>(w_t, wbt);
  k_tconv<<<dim3(57, 16), 256, 0, stream>>>(y2, x, wbt, b_t, g_t, be_t, m_t,
                                            v_t, outp);
}

// Round 14
// 367.516 us; speedup vs baseline: 3.1253x; 1.0248x over previous
//
#include <hip/hip_runtime.h>

// SSHA block. Round 14: k_attn3 micro-fixes (everything else = round 13):
//  (1) Xt4 padded [16][129] uint4 — kills the 8-way bank conflict on step-1
//      fragment reads (row stride 2048B = bank-aligned; 2064B = +4 banks).
//  (2) s-loop software-pipelined: step1(s+1) issued between the barriers
//      together with step2(s) (independent work) — 56 MFMAs per barrier
//      section instead of 32. Fully unrolled so accY double-buffer is free.
//  (3) y1-epilogue Yl stores packed as ushort4.
// Shapes: N=16, T=288, V=25, C=128, S=8, IC=16, W=3, U=75, TP=290.

#define NN 16
#define TT 288
#define VV 25
#define CC 128
#define SS 8
#define UU 75
#define TP 290
#define EPSF 1e-5f

typedef __attribute__((ext_vector_type(8))) short bf16x8;
typedef __attribute__((ext_vector_type(4))) float f32x4;

static __device__ __forceinline__ ushort f2bf(float f) {
  uint u = __float_as_uint(f);
  u = (u + 0x7FFFu + ((u >> 16) & 1u)) >> 16;
  return (ushort)u;
}

// ---------------- K0: weight converts ----------------
__global__ __launch_bounds__(256) void k_wcvt(
    const float* __restrict__ w_out, const float* __restrict__ w_k,
    const float* __restrict__ w_q, const float* __restrict__ w_ff,
    ushort* __restrict__ wb, ushort* __restrict__ wkqb,
    ushort* __restrict__ wffb) {
  int i = blockIdx.x * 256 + threadIdx.x;  // 180224 total
  if (i < 131072) {
    int j = i >> 7, c = i & 127;
    int s = j >> 7, o = j & 127;
    wb[i] = f2bf(w_out[(o << 10) + (s << 7) + c]);
  } else {
    int j = i - 131072;
    if (j < 16384) wkqb[j] = f2bf(w_k[j]);
    else if (j < 32768) wkqb[j] = f2bf(w_q[j - 16384]);
    else wffb[j - 32768] = f2bf(w_ff[j - 32768]);
  }
}

// ---------------- K1: k/q 1x1 convs as bf16 MFMA GEMM ----------------
__global__ __launch_bounds__(256) void k_qkg(
    const float* __restrict__ x, const ushort* __restrict__ wkqb,
    const float* __restrict__ b_k, const float* __restrict__ b_q,
    ushort* __restrict__ kb, ushort* __restrict__ qb) {
  __shared__ __align__(16) ushort As[8][128][8];
  __shared__ __align__(16) ushort Bs[8][128][8];
  const int bm = blockIdx.x, by = blockIdx.y;
  const int gm0 = bm << 7;
  const int tid = threadIdx.x;
  const int lane = tid & 63, wid = tid >> 6;
  const int wm = wid >> 1, wn = wid & 1;
  const int srow = tid & 127;
  const int skg0 = tid >> 7;
  const ushort* wsrc = wkqb + by * 16384;
  f32x4 acc[4][4] = {};
  for (int kh = 0; kh < 2; ++kh) {
    __syncthreads();
#pragma unroll
    for (int j = 0; j < 4; ++j) {
      int kg = skg0 + 2 * j;
      const float* xp = x + (((size_t)(gm0 + srow)) << 7) + kh * 64 + kg * 8;
      float4 a0 = *(const float4*)xp;
      float4 a1 = *(const float4*)(xp + 4);
      uint4 pk;
      pk.x = (uint)f2bf(a0.x) | ((uint)f2bf(a0.y) << 16);
      pk.y = (uint)f2bf(a0.z) | ((uint)f2bf(a0.w) << 16);
      pk.z = (uint)f2bf(a1.x) | ((uint)f2bf(a1.y) << 16);
      pk.w = (uint)f2bf(a1.z) | ((uint)f2bf(a1.w) << 16);
      *(uint4*)&As[kg][srow][0] = pk;
      *(uint4*)&Bs[kg][srow][0] =
          *(const uint4*)&wsrc[(srow << 7) + kh * 64 + kg * 8];
    }
    __syncthreads();
#pragma unroll
    for (int ks = 0; ks < 2; ++ks) {
      int g = ks * 4 + (lane >> 4);
      bf16x8 af[4], bfr[4];
#pragma unroll
      for (int mi = 0; mi < 4; ++mi)
        af[mi] = *(const bf16x8*)&As[g][wm * 64 + mi * 16 + (lane & 15)][0];
#pragma unroll
      for (int ni = 0; ni < 4; ++ni)
        bfr[ni] = *(const bf16x8*)&Bs[g][wn * 64 + ni * 16 + (lane & 15)][0];
#pragma unroll
      for (int mi = 0; mi < 4; ++mi)
#pragma unroll
        for (int ni = 0; ni < 4; ++ni)
          acc[mi][ni] = __builtin_amdgcn_mfma_f32_16x16x32_bf16(
              af[mi], bfr[ni], acc[mi][ni], 0, 0, 0);
    }
  }
  const int l15 = lane & 15, l4 = lane >> 4;
  const float* bias = by ? b_q : b_k;
#pragma unroll
  for (int ni = 0; ni < 4; ++ni) {
    int col = wn * 64 + ni * 16 + l15;
    float bb = bias[col];
#pragma unroll
    for (int mi = 0; mi < 4; ++mi) {
#pragma unroll
      for (int reg = 0; reg < 4; ++reg) {
        int row = gm0 + wm * 64 + mi * 16 + (l4 << 2) + reg;
        ushort val = f2bf(acc[mi][ni][reg] + bb);
        if (by == 0) {
          kb[((size_t)row << 7) + col] = val;
        } else {
          int n = row / 7200;
          qb[((size_t)(row + n * 50 + 25) << 7) + col] = val;
        }
      }
    }
  }
}

// qb pad rows (tp=0, tp=289): bias-only.
__global__ __launch_bounds__(256) void k_qkpad(const float* __restrict__ b_q,
                                               ushort* __restrict__ qb) {
  int i = blockIdx.x * 256 + threadIdx.x;  // 16*2*25*128
  int o = i & 127;
  int r = i >> 7;
  int v = r % 25;
  int e = (r / 25) & 1;
  int n = r / 50;
  int tp = e ? 289 : 0;
  qb[((size_t)((n * TP + tp) * VV + v) << 7) + o] = f2bf(b_q[o]);
}

// ---------------- K2: scores (bf16 MFMA) + fused softmax -> attTb bf16 ----------------
// attTb[n][s][v(25)][u'(96)] with u' = w*32+vp, zero at vp>=25.
__global__ __launch_bounds__(512) void k_scores(
    const ushort* __restrict__ kb, const ushort* __restrict__ qb,
    const float* __restrict__ alphas, const float* __restrict__ att0,
    ushort* __restrict__ attTb) {
  __shared__ float red[8][2640];  // [wave][u(80) * 33 + v(32)]
  __shared__ float scl[1875];
  __shared__ float mx[25];
  __shared__ float den[25];
  const int bx = blockIdx.x;
  const int n = bx >> 3, s = bx & 7;
  const int tid = threadIdx.x;
  const int lane = tid & 63, wid = tid >> 6;
  const int l15 = lane & 15, l4 = lane >> 4;
  const int dt = l4 >> 1;
  const int sic = s * 16 + (l4 & 1) * 8;
  int qoff[5];
#pragma unroll
  for (int tu = 0; tu < 5; ++tu) {
    int u = tu * 16 + l15;
    int w = u / 25, vp = u - w * 25;
    qoff[tu] = (w * 25 + vp) * 128 + sic;
  }
  const bool qv4 = (64 + l15) < 75;
  const bool kv1 = (16 + l15) < 25;
  int koff0 = l15 * 128 + sic;
  int koff1 = (16 + l15) * 128 + sic;
  const ushort* qbase = qb + (size_t)n * 928000 + (size_t)dt * 3200;
  const ushort* kbase = kb + (size_t)n * 921600 + (size_t)dt * 3200;
  f32x4 acc[5][2] = {};
  const bf16x8 zf = {};
  for (int kk = wid; kk < 144; kk += 8) {
    const ushort* qp = qbase + kk * 6400;
    const ushort* kp = kbase + kk * 6400;
    bf16x8 a[5], b[2];
#pragma unroll
    for (int tu = 0; tu < 4; ++tu) a[tu] = *(const bf16x8*)(qp + qoff[tu]);
    a[4] = qv4 ? *(const bf16x8*)(qp + qoff[4]) : zf;
    b[0] = *(const bf16x8*)(kp + koff0);
    b[1] = kv1 ? *(const bf16x8*)(kp + koff1) : zf;
#pragma unroll
    for (int tu = 0; tu < 5; ++tu)
#pragma unroll
      for (int tv = 0; tv < 2; ++tv)
        acc[tu][tv] = __builtin_amdgcn_mfma_f32_16x16x32_bf16(
            a[tu], b[tv], acc[tu][tv], 0, 0, 0);
  }
#pragma unroll
  for (int tu = 0; tu < 5; ++tu)
#pragma unroll
    for (int tv = 0; tv < 2; ++tv) {
#pragma unroll
      for (int reg = 0; reg < 4; ++reg)
        red[wid][(tu * 16 + l4 * 4 + reg) * 33 + tv * 16 + l15] =
            acc[tu][tv][reg];
    }
  __syncthreads();
  const float inv = 1.0f / 4608.0f;
  for (int i = tid; i < 1875; i += 512) {
    int u = i / 25, v = i - u * 25;
    float a = 0.f;
#pragma unroll
    for (int w = 0; w < 8; ++w) a += red[w][u * 33 + v];
    scl[i] = a * inv;
  }
  __syncthreads();
  if (tid < 25) {
    float m = -1e30f;
    for (int u = 0; u < 75; ++u) m = fmaxf(m, scl[u * 25 + tid]);
    float d = 0.f;
    for (int u = 0; u < 75; ++u) d += expf(scl[u * 25 + tid] - m);
    mx[tid] = m;
    den[tid] = d;
  }
  __syncthreads();
  const float alpha = alphas[s];
  ushort* op = attTb + (size_t)bx * 2400;
  for (int i = tid; i < 2400; i += 512) {
    int v = i / 96, u = i - v * 96;
    int w = u >> 5, vp = u & 31;
    float val = 0.f;
    if (vp < 25) {
      int uo = w * 25 + vp;
      val = expf(scl[uo * 25 + v] - mx[v]) / den[v] * alpha +
            att0[(s * 75 + uo) * 25 + v];
    }
    op[i] = f2bf(val);
  }
}

// ---------------- K3: attention-apply + out conv + FF conv (triple MFMA, TB=2) ----------------
// Grid (144, 16): 2 t per block. 256 thr = 4 waves; wave wid owns c-range
// (steps 1/2) and o-range (steps 2/3) [wid*32, wid*32+32).
// Xt4 [chunk][129] uint4 (padded: +4 banks/row). s-loop software-pipelined:
// step1(s+1) issued alongside step2(s) between the barriers.
__global__ __launch_bounds__(256, 3) void k_attn3(
    const float* __restrict__ x, const ushort* __restrict__ attTb,
    const ushort* __restrict__ wb, const float* __restrict__ b_out,
    const float* __restrict__ g_out, const float* __restrict__ beta_out,
    const float* __restrict__ m_out, const float* __restrict__ v_out,
    const ushort* __restrict__ wffb, const float* __restrict__ b_ff,
    const float* __restrict__ g_ff, const float* __restrict__ beta_ff,
    const float* __restrict__ m_ff, const float* __restrict__ v_ff,
    float* __restrict__ y2) {
  __shared__ __align__(16) uint4 Xt4[16 * 129];  // [chunk][c pad129]
  __shared__ __align__(16) ushort Yl[2][32 * 136];
  const int t0 = blockIdx.x * 2, n = blockIdx.y;
  const int tid = threadIdx.x;
  // stage Xt: chunk = r*4 + vp0/8 (r = t-row, tr = t0+r-1), c lane-fast.
  for (int i = tid; i < 2048; i += 256) {
    int c = i & 127, chunk = i >> 7;
    int r = chunk >> 2, vp0 = (chunk & 3) * 8;
    int tr = t0 + r - 1;
    bool valid = (tr >= 0 && tr < TT);
    const float* xr = x + (((size_t)(n * TT + tr) * VV)) * 128 + c;
    float f[8];
#pragma unroll
    for (int j = 0; j < 8; ++j) {
      int vp = vp0 + j;
      f[j] = (valid && vp < 25) ? xr[vp * 128] : 0.f;
    }
    uint4 pk;
    pk.x = (uint)f2bf(f[0]) | ((uint)f2bf(f[1]) << 16);
    pk.y = (uint)f2bf(f[2]) | ((uint)f2bf(f[3]) << 16);
    pk.z = (uint)f2bf(f[4]) | ((uint)f2bf(f[5]) << 16);
    pk.w = (uint)f2bf(f[6]) | ((uint)f2bf(f[7]) << 16);
    Xt4[chunk * 129 + c] = pk;
  }
  __syncthreads();
  const int lane = tid & 63, wid = tid >> 6;
  const int l15 = lane & 15, l4 = lane >> 4;
  const bf16x8 zf = {};
  f32x4 accO[2][2][2] = {};  // [tt][mi(o)][nj(v)]
  const ushort* Avn = attTb + (size_t)n * 19200;
  const int c0r = wid * 32 + l15, c1r = wid * 32 + 16 + l15;

  auto step1 = [&](int s, f32x4 (&accY)[2][2][2]) {
    const ushort* AvS = Avn + s * 2400;
#pragma unroll
    for (int ks = 0; ks < 3; ++ks) {
      int u0 = ks * 32 + l4 * 8;
      bf16x8 av0 = *(const bf16x8*)&AvS[l15 * 96 + u0];
      int r1 = 16 + l15;
      bf16x8 av1 = *(const bf16x8*)&AvS[(r1 <= 24 ? r1 : 24) * 96 + u0];
      if (l15 > 8) av1 = zf;  // v >= 25 -> zero row
#pragma unroll
      for (int tt = 0; tt < 2; ++tt) {
        int ch = (tt + ks) * 4 + l4;
        bf16x8 xb0 = *(const bf16x8*)&Xt4[ch * 129 + c0r];
        bf16x8 xb1 = *(const bf16x8*)&Xt4[ch * 129 + c1r];
        accY[tt][0][0] = __builtin_amdgcn_mfma_f32_16x16x32_bf16(av0, xb0, accY[tt][0][0], 0, 0, 0);
        accY[tt][0][1] = __builtin_amdgcn_mfma_f32_16x16x32_bf16(av0, xb1, accY[tt][0][1], 0, 0, 0);
        accY[tt][1][0] = __builtin_amdgcn_mfma_f32_16x16x32_bf16(av1, xb0, accY[tt][1][0], 0, 0, 0);
        accY[tt][1][1] = __builtin_amdgcn_mfma_f32_16x16x32_bf16(av1, xb1, accY[tt][1][1], 0, 0, 0);
      }
    }
  };

  f32x4 accYc[2][2][2] = {};
  step1(0, accYc);
#pragma unroll
  for (int s = 0; s < 8; ++s) {
    __syncthreads();  // previous step-2 readers done with Yl
#pragma unroll
    for (int tt = 0; tt < 2; ++tt)
#pragma unroll
      for (int mi = 0; mi < 2; ++mi)
#pragma unroll
        for (int nj = 0; nj < 2; ++nj)
#pragma unroll
          for (int reg = 0; reg < 4; ++reg)
            Yl[tt][(mi * 16 + l4 * 4 + reg) * 136 + wid * 32 + nj * 16 + l15] =
                f2bf(accYc[tt][mi][nj][reg]);
    __syncthreads();
    // pipelined: step1(s+1) + step2(s) between barriers (independent work)
    f32x4 accYn[2][2][2] = {};
    if (s < 7) step1(s + 1, accYn);
    const ushort* wS = wb + s * 16384;
#pragma unroll
    for (int kc = 0; kc < 4; ++kc) {
      int c0 = kc * 32 + l4 * 8;
      bf16x8 wf0 = *(const bf16x8*)&wS[(wid * 32 + l15) * 128 + c0];
      bf16x8 wf1 = *(const bf16x8*)&wS[(wid * 32 + 16 + l15) * 128 + c0];
#pragma unroll
      for (int tt = 0; tt < 2; ++tt) {
        bf16x8 yb0 = *(const bf16x8*)&Yl[tt][l15 * 136 + c0];
        bf16x8 yb1 = *(const bf16x8*)&Yl[tt][(16 + l15) * 136 + c0];
        accO[tt][0][0] = __builtin_amdgcn_mfma_f32_16x16x32_bf16(wf0, yb0, accO[tt][0][0], 0, 0, 0);
        accO[tt][0][1] = __builtin_amdgcn_mfma_f32_16x16x32_bf16(wf0, yb1, accO[tt][0][1], 0, 0, 0);
        accO[tt][1][0] = __builtin_amdgcn_mfma_f32_16x16x32_bf16(wf1, yb0, accO[tt][1][0], 0, 0, 0);
        accO[tt][1][1] = __builtin_amdgcn_mfma_f32_16x16x32_bf16(wf1, yb1, accO[tt][1][1], 0, 0, 0);
      }
    }
#pragma unroll
    for (int tt = 0; tt < 2; ++tt)
#pragma unroll
      for (int mi = 0; mi < 2; ++mi)
#pragma unroll
        for (int nj = 0; nj < 2; ++nj)
          accYc[tt][mi][nj] = accYn[tt][mi][nj];
  }
  // ---- y1 epilogue: BN + leaky(x + .), write bf16 to Yl (v>=25 rows = 0) ----
  __syncthreads();  // last step-2 Yl reads complete
#pragma unroll
  for (int tt = 0; tt < 2; ++tt) {
    int t = t0 + tt;
#pragma unroll
    for (int nj = 0; nj < 2; ++nj) {
      int v = nj * 16 + l15;
      ushort4 pv[2];
      if (v < 25) {
        size_t rowbase = (((size_t)(n * TT + t) * VV + v)) * 128 + wid * 32;
#pragma unroll
        for (int mi = 0; mi < 2; ++mi) {
          int ob = mi * 16 + (l4 << 2);
          int og = wid * 32 + ob;
          float4 gg = *(const float4*)&g_out[og];
          float4 vv = *(const float4*)&v_out[og];
          float4 mm = *(const float4*)&m_out[og];
          float4 be = *(const float4*)&beta_out[og];
          float4 bo = *(const float4*)&b_out[og];
          float4 xv = *(const float4*)&x[rowbase + ob];
          float s1, a;
          s1 = gg.x * rsqrtf(vv.x + EPSF);
          a = (accO[tt][mi][nj][0] + bo.x) * s1 + (be.x - mm.x * s1) + xv.x;
          pv[mi].x = f2bf(a > 0.f ? a : 0.1f * a);
          s1 = gg.y * rsqrtf(vv.y + EPSF);
          a = (accO[tt][mi][nj][1] + bo.y) * s1 + (be.y - mm.y * s1) + xv.y;
          pv[mi].y = f2bf(a > 0.f ? a : 0.1f * a);
          s1 = gg.z * rsqrtf(vv.z + EPSF);
          a = (accO[tt][mi][nj][2] + bo.z) * s1 + (be.z - mm.z * s1) + xv.z;
          pv[mi].z = f2bf(a > 0.f ? a : 0.1f * a);
          s1 = gg.w * rsqrtf(vv.w + EPSF);
          a = (accO[tt][mi][nj][3] + bo.w) * s1 + (be.w - mm.w * s1) + xv.w;
          pv[mi].w = f2bf(a > 0.f ? a : 0.1f * a);
        }
      } else {
        pv[0] = make_ushort4(0, 0, 0, 0);
        pv[1] = make_ushort4(0, 0, 0, 0);
      }
#pragma unroll
      for (int mi = 0; mi < 2; ++mi)
        *(ushort4*)&Yl[tt][v * 136 + wid * 32 + mi * 16 + (l4 << 2)] = pv[mi];
    }
  }
  __syncthreads();
  // ---- step 3: FF = W_ff . y1 (K=128) ----
  f32x4 accF[2][2][2] = {};  // [tt][mi(o)][nj(v)]
#pragma unroll
  for (int kc = 0; kc < 4; ++kc) {
    int c0 = kc * 32 + l4 * 8;
    bf16x8 wf0 = *(const bf16x8*)&wffb[(wid * 32 + l15) * 128 + c0];
    bf16x8 wf1 = *(const bf16x8*)&wffb[(wid * 32 + 16 + l15) * 128 + c0];
#pragma unroll
    for (int tt = 0; tt < 2; ++tt) {
      bf16x8 yb0 = *(const bf16x8*)&Yl[tt][l15 * 136 + c0];
      bf16x8 yb1 = *(const bf16x8*)&Yl[tt][(16 + l15) * 136 + c0];
      accF[tt][0][0] = __builtin_amdgcn_mfma_f32_16x16x32_bf16(wf0, yb0, accF[tt][0][0], 0, 0, 0);
      accF[tt][0][1] = __builtin_amdgcn_mfma_f32_16x16x32_bf16(wf0, yb1, accF[tt][0][1], 0, 0, 0);
      accF[tt][1][0] = __builtin_amdgcn_mfma_f32_16x16x32_bf16(wf1, yb0, accF[tt][1][0], 0, 0, 0);
      accF[tt][1][1] = __builtin_amdgcn_mfma_f32_16x16x32_bf16(wf1, yb1, accF[tt][1][1], 0, 0, 0);
    }
  }
  // ---- ff epilogue: y2 = leaky(x + BN_ff(FF + b_ff)) ----
#pragma unroll
  for (int tt = 0; tt < 2; ++tt) {
    int t = t0 + tt;
#pragma unroll
    for (int nj = 0; nj < 2; ++nj) {
      int v = nj * 16 + l15;
      if (v < 25) {
        size_t rowbase = (((size_t)(n * TT + t) * VV + v)) * 128 + wid * 32;
#pragma unroll
        for (int mi = 0; mi < 2; ++mi) {
          int ob = mi * 16 + (l4 << 2);
          int og = wid * 32 + ob;
          float4 gg = *(const float4*)&g_ff[og];
          float4 vv = *(const float4*)&v_ff[og];
          float4 mm = *(const float4*)&m_ff[og];
          float4 be = *(const float4*)&beta_ff[og];
          float4 bo = *(const float4*)&b_ff[og];
          float4 xv = *(const float4*)&x[rowbase + ob];
          float4 r;
          float s1, a;
          s1 = gg.x * rsqrtf(vv.x + EPSF);
          a = (accF[tt][mi][nj][0] + bo.x) * s1 + (be.x - mm.x * s1) + xv.x;
          r.x = a > 0.f ? a : 0.1f * a;
          s1 = gg.y * rsqrtf(vv.y + EPSF);
          a = (accF[tt][mi][nj][1] + bo.y) * s1 + (be.y - mm.y * s1) + xv.y;
          r.y = a > 0.f ? a : 0.1f * a;
          s1 = gg.z * rsqrtf(vv.z + EPSF);
          a = (accF[tt][mi][nj][2] + bo.z) * s1 + (be.z - mm.z * s1) + xv.z;
          r.z = a > 0.f ? a : 0.1f * a;
          s1 = gg.w * rsqrtf(vv.w + EPSF);
          a = (accF[tt][mi][nj][3] + bo.w) * s1 + (be.w - mm.w * s1) + xv.w;
          r.w = a > 0.f ? a : 0.1f * a;
          *(float4*)&y2[rowbase + ob] = r;
        }
      }
    }
  }
}

// ---------------- K5a: w_t (o,c,kt) -> bf16 wbt[o][kt*128+c] ----------------
__global__ __launch_bounds__(256) void k_wtb(const float* __restrict__ w_t,
                                             ushort* __restrict__ wbt) {
  int i = blockIdx.x * 256 + threadIdx.x;
  if (i < 128 * 128 * 7) {
    int o = i / 896;
    int rem = i - o * 896;
    int c = rem / 7, kt = rem - c * 7;
    wbt[o * 896 + kt * 128 + c] = f2bf(w_t[i]);
  }
}

// ---------------- K5: temporal conv as bf16 MFMA GEMM ----------------
__global__ __launch_bounds__(256, 2) void k_tconv(
    const float* __restrict__ y2, const float* __restrict__ x,
    const ushort* __restrict__ wbt, const float* __restrict__ b_t,
    const float* __restrict__ g_t, const float* __restrict__ beta_t,
    const float* __restrict__ m_t, const float* __restrict__ v_t,
    float* __restrict__ out) {
  __shared__ __align__(16) uint4 As[280 * 16];  // [row][16B-chunk], ^(row&7)
  const int n = blockIdx.y;
  const int r0 = blockIdx.x << 7;
  const int tid = threadIdx.x;
  const float* y2n = y2 + ((size_t)n * 7200 << 7);
  for (int i = tid; i < 278 * 16; i += 256) {
    int rl = i >> 4, cc = i & 15;
    int g = r0 - 75 + rl;
    uint4 pk = make_uint4(0u, 0u, 0u, 0u);
    if (g >= 0 && g < 7200) {
      const float* xp = y2n + ((size_t)g << 7) + (cc << 3);
      float4 a0 = *(const float4*)xp;
      float4 a1 = *(const float4*)(xp + 4);
      pk.x = (uint)f2bf(a0.x) | ((uint)f2bf(a0.y) << 16);
      pk.y = (uint)f2bf(a0.z) | ((uint)f2bf(a0.w) << 16);
      pk.z = (uint)f2bf(a1.x) | ((uint)f2bf(a1.y) << 16);
      pk.w = (uint)f2bf(a1.z) | ((uint)f2bf(a1.w) << 16);
    }
    As[(rl << 4) + (cc ^ (rl & 7))] = pk;
  }
  __syncthreads();
  const int lane = tid & 63, wid = tid >> 6;
  const int wm = wid >> 1, wn = wid & 1;
  const int l15 = lane & 15, l4 = lane >> 4;
  f32x4 acc[4][4] = {};
  for (int kt = 0; kt < 7; ++kt) {
    bf16x8 bfr[4][4];
#pragma unroll
    for (int ni = 0; ni < 4; ++ni) {
      const ushort* bp =
          wbt + (size_t)(wn * 64 + ni * 16 + l15) * 896 + kt * 128 + l4 * 8;
#pragma unroll
      for (int cc0 = 0; cc0 < 4; ++cc0)
        bfr[ni][cc0] = *(const bf16x8*)(bp + cc0 * 32);
    }
#pragma unroll
    for (int cc0 = 0; cc0 < 4; ++cc0) {
      bf16x8 af[4];
#pragma unroll
      for (int mi = 0; mi < 4; ++mi) {
        int rl = wm * 64 + mi * 16 + l15 + 25 * kt;
        af[mi] = *(const bf16x8*)&As[(rl << 4) + ((cc0 * 4 + l4) ^ (rl & 7))];
      }
#pragma unroll
      for (int mi = 0; mi < 4; ++mi)
#pragma unroll
        for (int ni = 0; ni < 4; ++ni)
          acc[mi][ni] = __builtin_amdgcn_mfma_f32_16x16x32_bf16(
              af[mi], bfr[ni][cc0], acc[mi][ni], 0, 0, 0);
    }
  }
#pragma unroll
  for (int ni = 0; ni < 4; ++ni) {
    int o = wn * 64 + ni * 16 + l15;
    float s1 = g_t[o] * rsqrtf(v_t[o] + EPSF);
    float sh = beta_t[o] - m_t[o] * s1;
    float bb = b_t[o];
#pragma unroll
    for (int mi = 0; mi < 4; ++mi) {
#pragma unroll
      for (int reg = 0; reg < 4; ++reg) {
        int grow = r0 + wm * 64 + mi * 16 + (l4 << 2) + reg;
        if (grow < 7200) {
          size_t idx = (((size_t)n * 7200 + grow) << 7) + o;
          float z = (acc[mi][ni][reg] + bb) * s1 + sh;
          z += y2[idx];
          z = z > 0.f ? z : 0.1f * z;
          z += x[idx];
          out[idx] = z > 0.f ? z : 0.f;
        }
      }
    }
  }
}

extern "C" void kernel_launch(void* const* d_in, const int* in_sizes, int n_in,
                              void* d_out, int out_size, void* d_ws, size_t ws_size,
                              hipStream_t stream) {
  const float* x      = (const float*)d_in[0];
  const float* w_k    = (const float*)d_in[1];
  const float* b_k    = (const float*)d_in[2];
  const float* w_q    = (const float*)d_in[3];
  const float* b_q    = (const float*)d_in[4];
  const float* alphas = (const float*)d_in[5];
  const float* att0   = (const float*)d_in[6];
  const float* w_out  = (const float*)d_in[7];
  const float* b_out  = (const float*)d_in[8];
  const float* g_out  = (const float*)d_in[9];
  const float* be_out = (const float*)d_in[10];
  const float* m_out  = (const float*)d_in[11];
  const float* v_out  = (const float*)d_in[12];
  const float* w_ff   = (const float*)d_in[13];
  const float* b_ff   = (const float*)d_in[14];
  const float* g_ff   = (const float*)d_in[15];
  const float* be_ff  = (const float*)d_in[16];
  const float* m_ff   = (const float*)d_in[17];
  const float* v_ff   = (const float*)d_in[18];
  const float* w_t    = (const float*)d_in[19];
  const float* b_t    = (const float*)d_in[20];
  const float* g_t    = (const float*)d_in[21];
  const float* be_t   = (const float*)d_in[22];
  const float* m_t    = (const float*)d_in[23];
  const float* v_t    = (const float*)d_in[24];

  float* ws = (float*)d_ws;
  // Region plan (floats), total 32,108,288 = round-1 proven footprint:
  float* qfull = ws;               // [0, 14848000)   qb bf16 -> y2
  float* kfull = ws + 14848000;    // [.., +14745600) kb bf16
  float* part  = ws + 29593600;    // [.., +2160000)  wb/wkqb/wffb bf16
  float* attr  = ws + 31753600;    // [.., +240000)   attTb bf16 (307200 sh)
  float* wtr   = ws + 31993600;    // [.., +114688)   wbt bf16
  ushort* qbb   = (ushort*)qfull;
  ushort* kbb   = (ushort*)kfull;
  ushort* wb    = (ushort*)part;            // 131072 shorts
  ushort* wkqb  = (ushort*)part + 131072;   //  32768 shorts
  ushort* wffb  = (ushort*)part + 163840;   //  16384 shorts
  ushort* attTb = (ushort*)attr;
  ushort* wbt   = (ushort*)wtr;
  float* y2 = qfull;
  float* outp = (float*)d_out;

  k_wcvt<<<704, 256, 0, stream>>>(w_out, w_k, w_q, w_ff, wb, wkqb, wffb);
  k_qkg<<<dim3(900, 2), 256, 0, stream>>>(x, wkqb, b_k, b_q, kbb, qbb);
  k_qkpad<<<400, 256, 0, stream>>>(b_q, qbb);
  k_scores<<<128, 512, 0, stream>>>(kbb, qbb, alphas, att0, attTb);
  k_attn3<<<dim3(144, 16), 256, 0, stream>>>(x, attTb, wb, b_out, g_out,
                                             be_out, m_out, v_out, wffb, b_ff,
                                             g_ff, be_ff, m_ff, v_ff, y2);
  k_wtb<<<448, 256, 0, stream>>>(w_t, wbt);
  k_tconv<<<dim3(57, 16), 256, 0, stream>>>(y2, x, wbt, b_t, g_t, be_t, m_t,
                                            v_t, outp);
}

// Round 15
// 367.296 us; speedup vs baseline: 3.1272x; 1.0006x over previous
//
#include <hip/hip_runtime.h>

// SSHA block. Round 15 (everything else = round 14):
//  (1) k_attn3 step-1 MFMA operand order swapped: mfma(X,A) gives D[c][v] so
//      the 4 C/D regs are column-consecutive in Yl[v][c] -> one ushort4 store
//      per tile (was 4 scalar ushort stores). v>=25 cols auto-zero (zeroed
//      B-rows). Step-2 and epilogues unchanged.
//  (2) k_wcvt + k_wtb + k_qkpad merged into a single k_prep launch.
// Shapes: N=16, T=288, V=25, C=128, S=8, IC=16, W=3, U=75, TP=290.

#define NN 16
#define TT 288
#define VV 25
#define CC 128
#define SS 8
#define UU 75
#define TP 290
#define EPSF 1e-5f

typedef __attribute__((ext_vector_type(8))) short bf16x8;
typedef __attribute__((ext_vector_type(4))) float f32x4;

static __device__ __forceinline__ ushort f2bf(float f) {
  uint u = __float_as_uint(f);
  u = (u + 0x7FFFu + ((u >> 16) & 1u)) >> 16;
  return (ushort)u;
}

// ---------------- K0: all weight converts + qb pad rows ----------------
__global__ __launch_bounds__(256) void k_prep(
    const float* __restrict__ w_out, const float* __restrict__ w_k,
    const float* __restrict__ w_q, const float* __restrict__ w_ff,
    const float* __restrict__ w_t, const float* __restrict__ b_q,
    ushort* __restrict__ wb, ushort* __restrict__ wkqb,
    ushort* __restrict__ wffb, ushort* __restrict__ wbt,
    ushort* __restrict__ qb) {
  int i = blockIdx.x * 256 + threadIdx.x;  // 397312 total
  if (i < 131072) {
    int j = i >> 7, c = i & 127;
    int s = j >> 7, o = j & 127;
    wb[i] = f2bf(w_out[(o << 10) + (s << 7) + c]);
  } else if (i < 163840) {
    int j = i - 131072;
    if (j < 16384) wkqb[j] = f2bf(w_k[j]);
    else wkqb[j] = f2bf(w_q[j - 16384]);
  } else if (i < 180224) {
    int j = i - 163840;
    wffb[j] = f2bf(w_ff[j]);
  } else if (i < 294912) {
    int j = i - 180224;
    int o = j / 896;
    int rem = j - o * 896;
    int c = rem / 7, kt = rem - c * 7;
    wbt[o * 896 + kt * 128 + c] = f2bf(w_t[j]);
  } else {
    int j = i - 294912;  // 102400: qb bias-only pad rows (tp=0, 289)
    int o = j & 127;
    int r = j >> 7;
    int v = r % 25;
    int e = (r / 25) & 1;
    int n = r / 50;
    int tp = e ? 289 : 0;
    qb[((size_t)((n * TP + tp) * VV + v) << 7) + o] = f2bf(b_q[o]);
  }
}

// ---------------- K1: k/q 1x1 convs as bf16 MFMA GEMM ----------------
__global__ __launch_bounds__(256) void k_qkg(
    const float* __restrict__ x, const ushort* __restrict__ wkqb,
    const float* __restrict__ b_k, const float* __restrict__ b_q,
    ushort* __restrict__ kb, ushort* __restrict__ qb) {
  __shared__ __align__(16) ushort As[8][128][8];
  __shared__ __align__(16) ushort Bs[8][128][8];
  const int bm = blockIdx.x, by = blockIdx.y;
  const int gm0 = bm << 7;
  const int tid = threadIdx.x;
  const int lane = tid & 63, wid = tid >> 6;
  const int wm = wid >> 1, wn = wid & 1;
  const int srow = tid & 127;
  const int skg0 = tid >> 7;
  const ushort* wsrc = wkqb + by * 16384;
  f32x4 acc[4][4] = {};
  for (int kh = 0; kh < 2; ++kh) {
    __syncthreads();
#pragma unroll
    for (int j = 0; j < 4; ++j) {
      int kg = skg0 + 2 * j;
      const float* xp = x + (((size_t)(gm0 + srow)) << 7) + kh * 64 + kg * 8;
      float4 a0 = *(const float4*)xp;
      float4 a1 = *(const float4*)(xp + 4);
      uint4 pk;
      pk.x = (uint)f2bf(a0.x) | ((uint)f2bf(a0.y) << 16);
      pk.y = (uint)f2bf(a0.z) | ((uint)f2bf(a0.w) << 16);
      pk.z = (uint)f2bf(a1.x) | ((uint)f2bf(a1.y) << 16);
      pk.w = (uint)f2bf(a1.z) | ((uint)f2bf(a1.w) << 16);
      *(uint4*)&As[kg][srow][0] = pk;
      *(uint4*)&Bs[kg][srow][0] =
          *(const uint4*)&wsrc[(srow << 7) + kh * 64 + kg * 8];
    }
    __syncthreads();
#pragma unroll
    for (int ks = 0; ks < 2; ++ks) {
      int g = ks * 4 + (lane >> 4);
      bf16x8 af[4], bfr[4];
#pragma unroll
      for (int mi = 0; mi < 4; ++mi)
        af[mi] = *(const bf16x8*)&As[g][wm * 64 + mi * 16 + (lane & 15)][0];
#pragma unroll
      for (int ni = 0; ni < 4; ++ni)
        bfr[ni] = *(const bf16x8*)&Bs[g][wn * 64 + ni * 16 + (lane & 15)][0];
#pragma unroll
      for (int mi = 0; mi < 4; ++mi)
#pragma unroll
        for (int ni = 0; ni < 4; ++ni)
          acc[mi][ni] = __builtin_amdgcn_mfma_f32_16x16x32_bf16(
              af[mi], bfr[ni], acc[mi][ni], 0, 0, 0);
    }
  }
  const int l15 = lane & 15, l4 = lane >> 4;
  const float* bias = by ? b_q : b_k;
#pragma unroll
  for (int ni = 0; ni < 4; ++ni) {
    int col = wn * 64 + ni * 16 + l15;
    float bb = bias[col];
#pragma unroll
    for (int mi = 0; mi < 4; ++mi) {
#pragma unroll
      for (int reg = 0; reg < 4; ++reg) {
        int row = gm0 + wm * 64 + mi * 16 + (l4 << 2) + reg;
        ushort val = f2bf(acc[mi][ni][reg] + bb);
        if (by == 0) {
          kb[((size_t)row << 7) + col] = val;
        } else {
          int n = row / 7200;
          qb[((size_t)(row + n * 50 + 25) << 7) + col] = val;
        }
      }
    }
  }
}

// ---------------- K2: scores (bf16 MFMA) + fused softmax -> attTb bf16 ----------------
// attTb[n][s][v(25)][u'(96)] with u' = w*32+vp, zero at vp>=25.
__global__ __launch_bounds__(512) void k_scores(
    const ushort* __restrict__ kb, const ushort* __restrict__ qb,
    const float* __restrict__ alphas, const float* __restrict__ att0,
    ushort* __restrict__ attTb) {
  __shared__ float red[8][2640];  // [wave][u(80) * 33 + v(32)]
  __shared__ float scl[1875];
  __shared__ float mx[25];
  __shared__ float den[25];
  const int bx = blockIdx.x;
  const int n = bx >> 3, s = bx & 7;
  const int tid = threadIdx.x;
  const int lane = tid & 63, wid = tid >> 6;
  const int l15 = lane & 15, l4 = lane >> 4;
  const int dt = l4 >> 1;
  const int sic = s * 16 + (l4 & 1) * 8;
  int qoff[5];
#pragma unroll
  for (int tu = 0; tu < 5; ++tu) {
    int u = tu * 16 + l15;
    int w = u / 25, vp = u - w * 25;
    qoff[tu] = (w * 25 + vp) * 128 + sic;
  }
  const bool qv4 = (64 + l15) < 75;
  const bool kv1 = (16 + l15) < 25;
  int koff0 = l15 * 128 + sic;
  int koff1 = (16 + l15) * 128 + sic;
  const ushort* qbase = qb + (size_t)n * 928000 + (size_t)dt * 3200;
  const ushort* kbase = kb + (size_t)n * 921600 + (size_t)dt * 3200;
  f32x4 acc[5][2] = {};
  const bf16x8 zf = {};
  for (int kk = wid; kk < 144; kk += 8) {
    const ushort* qp = qbase + kk * 6400;
    const ushort* kp = kbase + kk * 6400;
    bf16x8 a[5], b[2];
#pragma unroll
    for (int tu = 0; tu < 4; ++tu) a[tu] = *(const bf16x8*)(qp + qoff[tu]);
    a[4] = qv4 ? *(const bf16x8*)(qp + qoff[4]) : zf;
    b[0] = *(const bf16x8*)(kp + koff0);
    b[1] = kv1 ? *(const bf16x8*)(kp + koff1) : zf;
#pragma unroll
    for (int tu = 0; tu < 5; ++tu)
#pragma unroll
      for (int tv = 0; tv < 2; ++tv)
        acc[tu][tv] = __builtin_amdgcn_mfma_f32_16x16x32_bf16(
            a[tu], b[tv], acc[tu][tv], 0, 0, 0);
  }
#pragma unroll
  for (int tu = 0; tu < 5; ++tu)
#pragma unroll
    for (int tv = 0; tv < 2; ++tv) {
#pragma unroll
      for (int reg = 0; reg < 4; ++reg)
        red[wid][(tu * 16 + l4 * 4 + reg) * 33 + tv * 16 + l15] =
            acc[tu][tv][reg];
    }
  __syncthreads();
  const float inv = 1.0f / 4608.0f;
  for (int i = tid; i < 1875; i += 512) {
    int u = i / 25, v = i - u * 25;
    float a = 0.f;
#pragma unroll
    for (int w = 0; w < 8; ++w) a += red[w][u * 33 + v];
    scl[i] = a * inv;
  }
  __syncthreads();
  if (tid < 25) {
    float m = -1e30f;
    for (int u = 0; u < 75; ++u) m = fmaxf(m, scl[u * 25 + tid]);
    float d = 0.f;
    for (int u = 0; u < 75; ++u) d += expf(scl[u * 25 + tid] - m);
    mx[tid] = m;
    den[tid] = d;
  }
  __syncthreads();
  const float alpha = alphas[s];
  ushort* op = attTb + (size_t)bx * 2400;
  for (int i = tid; i < 2400; i += 512) {
    int v = i / 96, u = i - v * 96;
    int w = u >> 5, vp = u & 31;
    float val = 0.f;
    if (vp < 25) {
      int uo = w * 25 + vp;
      val = expf(scl[uo * 25 + v] - mx[v]) / den[v] * alpha +
            att0[(s * 75 + uo) * 25 + v];
    }
    op[i] = f2bf(val);
  }
}

// ---------------- K3: attention-apply + out conv + FF conv (triple MFMA, TB=2) ----------------
// Grid (144, 16): 2 t per block. 256 thr = 4 waves; wave wid owns c-range
// (steps 1/2) and o-range (steps 2/3) [wid*32, wid*32+32).
// step1 computes D[c][v] = mfma(X, A) so Yl[v][c] stores pack as ushort4.
__global__ __launch_bounds__(256, 3) void k_attn3(
    const float* __restrict__ x, const ushort* __restrict__ attTb,
    const ushort* __restrict__ wb, const float* __restrict__ b_out,
    const float* __restrict__ g_out, const float* __restrict__ beta_out,
    const float* __restrict__ m_out, const float* __restrict__ v_out,
    const ushort* __restrict__ wffb, const float* __restrict__ b_ff,
    const float* __restrict__ g_ff, const float* __restrict__ beta_ff,
    const float* __restrict__ m_ff, const float* __restrict__ v_ff,
    float* __restrict__ y2) {
  __shared__ __align__(16) uint4 Xt4[16 * 129];  // [chunk][c pad129]
  __shared__ __align__(16) ushort Yl[2][32 * 136];
  const int t0 = blockIdx.x * 2, n = blockIdx.y;
  const int tid = threadIdx.x;
  // stage Xt: chunk = r*4 + vp0/8 (r = t-row, tr = t0+r-1), c lane-fast.
  for (int i = tid; i < 2048; i += 256) {
    int c = i & 127, chunk = i >> 7;
    int r = chunk >> 2, vp0 = (chunk & 3) * 8;
    int tr = t0 + r - 1;
    bool valid = (tr >= 0 && tr < TT);
    const float* xr = x + (((size_t)(n * TT + tr) * VV)) * 128 + c;
    float f[8];
#pragma unroll
    for (int j = 0; j < 8; ++j) {
      int vp = vp0 + j;
      f[j] = (valid && vp < 25) ? xr[vp * 128] : 0.f;
    }
    uint4 pk;
    pk.x = (uint)f2bf(f[0]) | ((uint)f2bf(f[1]) << 16);
    pk.y = (uint)f2bf(f[2]) | ((uint)f2bf(f[3]) << 16);
    pk.z = (uint)f2bf(f[4]) | ((uint)f2bf(f[5]) << 16);
    pk.w = (uint)f2bf(f[6]) | ((uint)f2bf(f[7]) << 16);
    Xt4[chunk * 129 + c] = pk;
  }
  __syncthreads();
  const int lane = tid & 63, wid = tid >> 6;
  const int l15 = lane & 15, l4 = lane >> 4;
  const bf16x8 zf = {};
  f32x4 accO[2][2][2] = {};  // [tt][mi(o)][nj(v)]
  const ushort* Avn = attTb + (size_t)n * 19200;
  const int c0r = wid * 32 + l15, c1r = wid * 32 + 16 + l15;

  // step1: accY[tt][cmi][vnj] = D[c][v], A = X rows c, B = Av rows v.
  auto step1 = [&](int s, f32x4 (&accY)[2][2][2]) {
    const ushort* AvS = Avn + s * 2400;
#pragma unroll
    for (int ks = 0; ks < 3; ++ks) {
      int u0 = ks * 32 + l4 * 8;
      bf16x8 av0 = *(const bf16x8*)&AvS[l15 * 96 + u0];
      int r1 = 16 + l15;
      bf16x8 av1 = *(const bf16x8*)&AvS[(r1 <= 24 ? r1 : 24) * 96 + u0];
      if (l15 > 8) av1 = zf;  // v >= 25 -> zero row
#pragma unroll
      for (int tt = 0; tt < 2; ++tt) {
        int ch = (tt + ks) * 4 + l4;
        bf16x8 xb0 = *(const bf16x8*)&Xt4[ch * 129 + c0r];
        bf16x8 xb1 = *(const bf16x8*)&Xt4[ch * 129 + c1r];
        accY[tt][0][0] = __builtin_amdgcn_mfma_f32_16x16x32_bf16(xb0, av0, accY[tt][0][0], 0, 0, 0);
        accY[tt][0][1] = __builtin_amdgcn_mfma_f32_16x16x32_bf16(xb0, av1, accY[tt][0][1], 0, 0, 0);
        accY[tt][1][0] = __builtin_amdgcn_mfma_f32_16x16x32_bf16(xb1, av0, accY[tt][1][0], 0, 0, 0);
        accY[tt][1][1] = __builtin_amdgcn_mfma_f32_16x16x32_bf16(xb1, av1, accY[tt][1][1], 0, 0, 0);
      }
    }
  };

  f32x4 accYc[2][2][2] = {};
  step1(0, accYc);
#pragma unroll
  for (int s = 0; s < 8; ++s) {
    __syncthreads();  // previous step-2 readers done with Yl
    // Yl[v][c] stores: thread holds c = wid*32+cmi*16+l4*4+reg (reg fast),
    // v = vnj*16 + l15 -> one ushort4 per tile.
#pragma unroll
    for (int tt = 0; tt < 2; ++tt)
#pragma unroll
      for (int cmi = 0; cmi < 2; ++cmi)
#pragma unroll
        for (int vnj = 0; vnj < 2; ++vnj) {
          ushort4 p;
          p.x = f2bf(accYc[tt][cmi][vnj][0]);
          p.y = f2bf(accYc[tt][cmi][vnj][1]);
          p.z = f2bf(accYc[tt][cmi][vnj][2]);
          p.w = f2bf(accYc[tt][cmi][vnj][3]);
          *(ushort4*)&Yl[tt][(vnj * 16 + l15) * 136 + wid * 32 + cmi * 16 +
                             (l4 << 2)] = p;
        }
    __syncthreads();
    // pipelined: step1(s+1) + step2(s) between barriers (independent work)
    f32x4 accYn[2][2][2] = {};
    if (s < 7) step1(s + 1, accYn);
    const ushort* wS = wb + s * 16384;
#pragma unroll
    for (int kc = 0; kc < 4; ++kc) {
      int c0 = kc * 32 + l4 * 8;
      bf16x8 wf0 = *(const bf16x8*)&wS[(wid * 32 + l15) * 128 + c0];
      bf16x8 wf1 = *(const bf16x8*)&wS[(wid * 32 + 16 + l15) * 128 + c0];
#pragma unroll
      for (int tt = 0; tt < 2; ++tt) {
        bf16x8 yb0 = *(const bf16x8*)&Yl[tt][l15 * 136 + c0];
        bf16x8 yb1 = *(const bf16x8*)&Yl[tt][(16 + l15) * 136 + c0];
        accO[tt][0][0] = __builtin_amdgcn_mfma_f32_16x16x32_bf16(wf0, yb0, accO[tt][0][0], 0, 0, 0);
        accO[tt][0][1] = __builtin_amdgcn_mfma_f32_16x16x32_bf16(wf0, yb1, accO[tt][0][1], 0, 0, 0);
        accO[tt][1][0] = __builtin_amdgcn_mfma_f32_16x16x32_bf16(wf1, yb0, accO[tt][1][0], 0, 0, 0);
        accO[tt][1][1] = __builtin_amdgcn_mfma_f32_16x16x32_bf16(wf1, yb1, accO[tt][1][1], 0, 0, 0);
      }
    }
#pragma unroll
    for (int tt = 0; tt < 2; ++tt)
#pragma unroll
      for (int mi = 0; mi < 2; ++mi)
#pragma unroll
        for (int nj = 0; nj < 2; ++nj)
          accYc[tt][mi][nj] = accYn[tt][mi][nj];
  }
  // ---- y1 epilogue: BN + leaky(x + .), write bf16 to Yl (v>=25 rows = 0) ----
  __syncthreads();  // last step-2 Yl reads complete
#pragma unroll
  for (int tt = 0; tt < 2; ++tt) {
    int t = t0 + tt;
#pragma unroll
    for (int nj = 0; nj < 2; ++nj) {
      int v = nj * 16 + l15;
      ushort4 pv[2];
      if (v < 25) {
        size_t rowbase = (((size_t)(n * TT + t) * VV + v)) * 128 + wid * 32;
#pragma unroll
        for (int mi = 0; mi < 2; ++mi) {
          int ob = mi * 16 + (l4 << 2);
          int og = wid * 32 + ob;
          float4 gg = *(const float4*)&g_out[og];
          float4 vv = *(const float4*)&v_out[og];
          float4 mm = *(const float4*)&m_out[og];
          float4 be = *(const float4*)&beta_out[og];
          float4 bo = *(const float4*)&b_out[og];
          float4 xv = *(const float4*)&x[rowbase + ob];
          float s1, a;
          s1 = gg.x * rsqrtf(vv.x + EPSF);
          a = (accO[tt][mi][nj][0] + bo.x) * s1 + (be.x - mm.x * s1) + xv.x;
          pv[mi].x = f2bf(a > 0.f ? a : 0.1f * a);
          s1 = gg.y * rsqrtf(vv.y + EPSF);
          a = (accO[tt][mi][nj][1] + bo.y) * s1 + (be.y - mm.y * s1) + xv.y;
          pv[mi].y = f2bf(a > 0.f ? a : 0.1f * a);
          s1 = gg.z * rsqrtf(vv.z + EPSF);
          a = (accO[tt][mi][nj][2] + bo.z) * s1 + (be.z - mm.z * s1) + xv.z;
          pv[mi].z = f2bf(a > 0.f ? a : 0.1f * a);
          s1 = gg.w * rsqrtf(vv.w + EPSF);
          a = (accO[tt][mi][nj][3] + bo.w) * s1 + (be.w - mm.w * s1) + xv.w;
          pv[mi].w = f2bf(a > 0.f ? a : 0.1f * a);
        }
      } else {
        pv[0] = make_ushort4(0, 0, 0, 0);
        pv[1] = make_ushort4(0, 0, 0, 0);
      }
#pragma unroll
      for (int mi = 0; mi < 2; ++mi)
        *(ushort4*)&Yl[tt][v * 136 + wid * 32 + mi * 16 + (l4 << 2)] = pv[mi];
    }
  }
  __syncthreads();
  // ---- step 3: FF = W_ff . y1 (K=128) ----
  f32x4 accF[2][2][2] = {};  // [tt][mi(o)][nj(v)]
#pragma unroll
  for (int kc = 0; kc < 4; ++kc) {
    int c0 = kc * 32 + l4 * 8;
    bf16x8 wf0 = *(const bf16x8*)&wffb[(wid * 32 + l15) * 128 + c0];
    bf16x8 wf1 = *(const bf16x8*)&wffb[(wid * 32 + 16 + l15) * 128 + c0];
#pragma unroll
    for (int tt = 0; tt < 2; ++tt) {
      bf16x8 yb0 = *(const bf16x8*)&Yl[tt][l15 * 136 + c0];
      bf16x8 yb1 = *(const bf16x8*)&Yl[tt][(16 + l15) * 136 + c0];
      accF[tt][0][0] = __builtin_amdgcn_mfma_f32_16x16x32_bf16(wf0, yb0, accF[tt][0][0], 0, 0, 0);
      accF[tt][0][1] = __builtin_amdgcn_mfma_f32_16x16x32_bf16(wf0, yb1, accF[tt][0][1], 0, 0, 0);
      accF[tt][1][0] = __builtin_amdgcn_mfma_f32_16x16x32_bf16(wf1, yb0, accF[tt][1][0], 0, 0, 0);
      accF[tt][1][1] = __builtin_amdgcn_mfma_f32_16x16x32_bf16(wf1, yb1, accF[tt][1][1], 0, 0, 0);
    }
  }
  // ---- ff epilogue: y2 = leaky(x + BN_ff(FF + b_ff)) ----
#pragma unroll
  for (int tt = 0; tt < 2; ++tt) {
    int t = t0 + tt;
#pragma unroll
    for (int nj = 0; nj < 2; ++nj) {
      int v = nj * 16 + l15;
      if (v < 25) {
        size_t rowbase = (((size_t)(n * TT + t) * VV + v)) * 128 + wid * 32;
#pragma unroll
        for (int mi = 0; mi < 2; ++mi) {
          int ob = mi * 16 + (l4 << 2);
          int og = wid * 32 + ob;
          float4 gg = *(const float4*)&g_ff[og];
          float4 vv = *(const float4*)&v_ff[og];
          float4 mm = *(const float4*)&m_ff[og];
          float4 be = *(const float4*)&beta_ff[og];
          float4 bo = *(const float4*)&b_ff[og];
          float4 xv = *(const float4*)&x[rowbase + ob];
          float4 r;
          float s1, a;
          s1 = gg.x * rsqrtf(vv.x + EPSF);
          a = (accF[tt][mi][nj][0] + bo.x) * s1 + (be.x - mm.x * s1) + xv.x;
          r.x = a > 0.f ? a : 0.1f * a;
          s1 = gg.y * rsqrtf(vv.y + EPSF);
          a = (accF[tt][mi][nj][1] + bo.y) * s1 + (be.y - mm.y * s1) + xv.y;
          r.y = a > 0.f ? a : 0.1f * a;
          s1 = gg.z * rsqrtf(vv.z + EPSF);
          a = (accF[tt][mi][nj][2] + bo.z) * s1 + (be.z - mm.z * s1) + xv.z;
          r.z = a > 0.f ? a : 0.1f * a;
          s1 = gg.w * rsqrtf(vv.w + EPSF);
          a = (accF[tt][mi][nj][3] + bo.w) * s1 + (be.w - mm.w * s1) + xv.w;
          r.w = a > 0.f ? a : 0.1f * a;
          *(float4*)&y2[rowbase + ob] = r;
        }
      }
    }
  }
}

// ---------------- K5: temporal conv as bf16 MFMA GEMM ----------------
__global__ __launch_bounds__(256, 2) void k_tconv(
    const float* __restrict__ y2, const float* __restrict__ x,
    const ushort* __restrict__ wbt, const float* __restrict__ b_t,
    const float* __restrict__ g_t, const float* __restrict__ beta_t,
    const float* __restrict__ m_t, const float* __restrict__ v_t,
    float* __restrict__ out) {
  __shared__ __align__(16) uint4 As[280 * 16];  // [row][16B-chunk], ^(row&7)
  const int n = blockIdx.y;
  const int r0 = blockIdx.x << 7;
  const int tid = threadIdx.x;
  const float* y2n = y2 + ((size_t)n * 7200 << 7);
  for (int i = tid; i < 278 * 16; i += 256) {
    int rl = i >> 4, cc = i & 15;
    int g = r0 - 75 + rl;
    uint4 pk = make_uint4(0u, 0u, 0u, 0u);
    if (g >= 0 && g < 7200) {
      const float* xp = y2n + ((size_t)g << 7) + (cc << 3);
      float4 a0 = *(const float4*)xp;
      float4 a1 = *(const float4*)(xp + 4);
      pk.x = (uint)f2bf(a0.x) | ((uint)f2bf(a0.y) << 16);
      pk.y = (uint)f2bf(a0.z) | ((uint)f2bf(a0.w) << 16);
      pk.z = (uint)f2bf(a1.x) | ((uint)f2bf(a1.y) << 16);
      pk.w = (uint)f2bf(a1.z) | ((uint)f2bf(a1.w) << 16);
    }
    As[(rl << 4) + (cc ^ (rl & 7))] = pk;
  }
  __syncthreads();
  const int lane = tid & 63, wid = tid >> 6;
  const int wm = wid >> 1, wn = wid & 1;
  const int l15 = lane & 15, l4 = lane >> 4;
  f32x4 acc[4][4] = {};
  for (int kt = 0; kt < 7; ++kt) {
    bf16x8 bfr[4][4];
#pragma unroll
    for (int ni = 0; ni < 4; ++ni) {
      const ushort* bp =
          wbt + (size_t)(wn * 64 + ni * 16 + l15) * 896 + kt * 128 + l4 * 8;
#pragma unroll
      for (int cc0 = 0; cc0 < 4; ++cc0)
        bfr[ni][cc0] = *(const bf16x8*)(bp + cc0 * 32);
    }
#pragma unroll
    for (int cc0 = 0; cc0 < 4; ++cc0) {
      bf16x8 af[4];
#pragma unroll
      for (int mi = 0; mi < 4; ++mi) {
        int rl = wm * 64 + mi * 16 + l15 + 25 * kt;
        af[mi] = *(const bf16x8*)&As[(rl << 4) + ((cc0 * 4 + l4) ^ (rl & 7))];
      }
#pragma unroll
      for (int mi = 0; mi < 4; ++mi)
#pragma unroll
        for (int ni = 0; ni < 4; ++ni)
          acc[mi][ni] = __builtin_amdgcn_mfma_f32_16x16x32_bf16(
              af[mi], bfr[ni][cc0], acc[mi][ni], 0, 0, 0);
    }
  }
#pragma unroll
  for (int ni = 0; ni < 4; ++ni) {
    int o = wn * 64 + ni * 16 + l15;
    float s1 = g_t[o] * rsqrtf(v_t[o] + EPSF);
    float sh = beta_t[o] - m_t[o] * s1;
    float bb = b_t[o];
#pragma unroll
    for (int mi = 0; mi < 4; ++mi) {
#pragma unroll
      for (int reg = 0; reg < 4; ++reg) {
        int grow = r0 + wm * 64 + mi * 16 + (l4 << 2) + reg;
        if (grow < 7200) {
          size_t idx = (((size_t)n * 7200 + grow) << 7) + o;
          float z = (acc[mi][ni][reg] + bb) * s1 + sh;
          z += y2[idx];
          z = z > 0.f ? z : 0.1f * z;
          z += x[idx];
          out[idx] = z > 0.f ? z : 0.f;
        }
      }
    }
  }
}

extern "C" void kernel_launch(void* const* d_in, const int* in_sizes, int n_in,
                              void* d_out, int out_size, void* d_ws, size_t ws_size,
                              hipStream_t stream) {
  const float* x      = (const float*)d_in[0];
  const float* w_k    = (const float*)d_in[1];
  const float* b_k    = (const float*)d_in[2];
  const float* w_q    = (const float*)d_in[3];
  const float* b_q    = (const float*)d_in[4];
  const float* alphas = (const float*)d_in[5];
  const float* att0   = (const float*)d_in[6];
  const float* w_out  = (const float*)d_in[7];
  const float* b_out  = (const float*)d_in[8];
  const float* g_out  = (const float*)d_in[9];
  const float* be_out = (const float*)d_in[10];
  const float* m_out  = (const float*)d_in[11];
  const float* v_out  = (const float*)d_in[12];
  const float* w_ff   = (const float*)d_in[13];
  const float* b_ff   = (const float*)d_in[14];
  const float* g_ff   = (const float*)d_in[15];
  const float* be_ff  = (const float*)d_in[16];
  const float* m_ff   = (const float*)d_in[17];
  const float* v_ff   = (const float*)d_in[18];
  const float* w_t    = (const float*)d_in[19];
  const float* b_t    = (const float*)d_in[20];
  const float* g_t    = (const float*)d_in[21];
  const float* be_t   = (const float*)d_in[22];
  const float* m_t    = (const float*)d_in[23];
  const float* v_t    = (const float*)d_in[24];

  float* ws = (float*)d_ws;
  // Region plan (floats), total 32,108,288 = round-1 proven footprint:
  float* qfull = ws;               // [0, 14848000)   qb bf16 -> y2
  float* kfull = ws + 14848000;    // [.., +14745600) kb bf16
  float* part  = ws + 29593600;    // [.., +2160000)  wb/wkqb/wffb bf16
  float* attr  = ws + 31753600;    // [.., +240000)   attTb bf16 (307200 sh)
  float* wtr   = ws + 31993600;    // [.., +114688)   wbt bf16
  ushort* qbb   = (ushort*)qfull;
  ushort* kbb   = (ushort*)kfull;
  ushort* wb    = (ushort*)part;            // 131072 shorts
  ushort* wkqb  = (ushort*)part + 131072;   //  32768 shorts
  ushort* wffb  = (ushort*)part + 163840;   //  16384 shorts
  ushort* attTb = (ushort*)attr;
  ushort* wbt   = (ushort*)wtr;
  float* y2 = qfull;
  float* outp = (float*)d_out;

  k_prep<<<1552, 256, 0, stream>>>(w_out, w_k, w_q, w_ff, w_t, b_q, wb, wkqb,
                                   wffb, wbt, qbb);
  k_qkg<<<dim3(900, 2), 256, 0, stream>>>(x, wkqb, b_k, b_q, kbb, qbb);
  k_scores<<<128, 512, 0, stream>>>(kbb, qbb, alphas, att0, attTb);
  k_attn3<<<dim3(144, 16), 256, 0, stream>>>(x, attTb, wb, b_out, g_out,
                                             be_out, m_out, v_out, wffb, b_ff,
                                             g_ff, be_ff, m_ff, v_ff, y2);
  k_tconv<<<dim3(57, 16), 256, 0, stream>>>(y2, x, wbt, b_t, g_t, be_t, m_t,
                                            v_t, outp);
}